// Round 1
// baseline (7917.900 us; speedup 1.0000x reference)
//
#include <hip/hip_runtime.h>
#include <math.h>

#define CDIV(a,b) (((a)+(b)-1)/(b))

// ============================ generic GEMM =================================
// C[M,N] = alpha * A[M,K] @ B (+ bias) (+ gelu) (+ C)
// TRANSB=false: B is [K,N] row-major (ldb); TRANSB=true: B is [N,K] row-major (ldb)
// EPI: 0 none, 1 +bias, 2 +bias then exact gelu, 3 +bias then += C
// batched via gridDim.z: z -> (bb=z/nh, hh=z%nh), offsets bb*s?b + hh*s?h
template<bool TRANSB, int EPI>
__global__ __launch_bounds__(256) void gemm_k(
    const float* __restrict__ A, int lda,
    const float* __restrict__ B, int ldb,
    float* __restrict__ C, int ldc,
    const float* __restrict__ bias,
    int M, int N, int K, float alpha, int nh,
    long sAb, long sAh, long sBb, long sBh, long sCb, long sCh)
{
    const int z = blockIdx.z;
    const int bb = z / nh, hh = z - bb * nh;
    A += bb * sAb + hh * sAh;
    B += bb * sBb + hh * sBh;
    C += bb * sCb + hh * sCh;

    __shared__ __align__(16) float As[16][64];
    __shared__ __align__(16) float Bs[16][64];

    const int tid = threadIdx.x;
    const int m0 = blockIdx.y * 64;
    const int n0 = blockIdx.x * 64;
    const int ty = tid >> 4, tx = tid & 15;

    float acc[4][4] = {};

    for (int k0 = 0; k0 < K; k0 += 16) {
        // ---- stage A tile (64 rows x 16 k), K-major in LDS ----
        {
            const int r = tid >> 2, kq = (tid & 3) << 2;
            const int gm = m0 + r, gk = k0 + kq;
            float v[4] = {0.f, 0.f, 0.f, 0.f};
            if (gm < M) {
                if (gk + 3 < K) {
                    const float4 f = *reinterpret_cast<const float4*>(A + (long)gm * lda + gk);
                    v[0] = f.x; v[1] = f.y; v[2] = f.z; v[3] = f.w;
                } else {
                    #pragma unroll
                    for (int j = 0; j < 4; ++j)
                        if (gk + j < K) v[j] = A[(long)gm * lda + gk + j];
                }
            }
            #pragma unroll
            for (int j = 0; j < 4; ++j) As[kq + j][r] = v[j];
        }
        // ---- stage B tile (16 k x 64 n) ----
        if (!TRANSB) {
            const int kr = tid >> 4, nq = (tid & 15) << 2;
            const int gk = k0 + kr, gn = n0 + nq;
            float v[4] = {0.f, 0.f, 0.f, 0.f};
            if (gk < K) {
                if (gn + 3 < N) {
                    const float4 f = *reinterpret_cast<const float4*>(B + (long)gk * ldb + gn);
                    v[0] = f.x; v[1] = f.y; v[2] = f.z; v[3] = f.w;
                } else {
                    #pragma unroll
                    for (int j = 0; j < 4; ++j)
                        if (gn + j < N) v[j] = B[(long)gk * ldb + gn + j];
                }
            }
            #pragma unroll
            for (int j = 0; j < 4; ++j) Bs[kr][nq + j] = v[j];
        } else {
            const int nr = tid >> 2, kq = (tid & 3) << 2;
            const int gn = n0 + nr, gk = k0 + kq;
            float v[4] = {0.f, 0.f, 0.f, 0.f};
            if (gn < N) {
                if (gk + 3 < K) {
                    const float4 f = *reinterpret_cast<const float4*>(B + (long)gn * ldb + gk);
                    v[0] = f.x; v[1] = f.y; v[2] = f.z; v[3] = f.w;
                } else {
                    #pragma unroll
                    for (int j = 0; j < 4; ++j)
                        if (gk + j < K) v[j] = B[(long)gn * ldb + gk + j];
                }
            }
            #pragma unroll
            for (int j = 0; j < 4; ++j) Bs[kq + j][nr] = v[j];
        }
        __syncthreads();

        #pragma unroll
        for (int kk = 0; kk < 16; ++kk) {
            const float4 a4 = *reinterpret_cast<const float4*>(&As[kk][ty << 2]);
            const float4 b4 = *reinterpret_cast<const float4*>(&Bs[kk][tx << 2]);
            const float av[4] = {a4.x, a4.y, a4.z, a4.w};
            const float bv[4] = {b4.x, b4.y, b4.z, b4.w};
            #pragma unroll
            for (int i = 0; i < 4; ++i)
                #pragma unroll
                for (int j = 0; j < 4; ++j)
                    acc[i][j] = fmaf(av[i], bv[j], acc[i][j]);
        }
        __syncthreads();
    }

    #pragma unroll
    for (int i = 0; i < 4; ++i) {
        const int gm = m0 + (ty << 2) + i;
        if (gm >= M) continue;
        #pragma unroll
        for (int j = 0; j < 4; ++j) {
            const int gn = n0 + (tx << 2) + j;
            if (gn >= N) continue;
            float v = acc[i][j] * alpha;
            if (EPI >= 1) v += bias[gn];
            if (EPI == 2) v = 0.5f * v * (1.0f + erff(v * 0.70710678118654752f));
            const long ci = (long)gm * ldc + gn;
            if (EPI == 3) v += C[ci];
            C[ci] = v;
        }
    }
}

static inline void gemm(hipStream_t st, bool transB, int epi,
                        const float* A, int lda, const float* B, int ldb,
                        float* C, int ldc, const float* bias,
                        int M, int N, int K, float alpha,
                        int batch, int nh,
                        long sAb, long sAh, long sBb, long sBh, long sCb, long sCh)
{
    dim3 g(CDIV(N, 64), CDIV(M, 64), batch);
    dim3 b(256);
#define GK_DISPATCH(TB, E) gemm_k<TB, E><<<g, b, 0, st>>>(A, lda, B, ldb, C, ldc, bias, M, N, K, alpha, nh, sAb, sAh, sBb, sBh, sCb, sCh)
    if (!transB) {
        switch (epi) {
            case 0: GK_DISPATCH(false, 0); break;
            case 1: GK_DISPATCH(false, 1); break;
            case 2: GK_DISPATCH(false, 2); break;
            default: GK_DISPATCH(false, 3); break;
        }
    } else {
        switch (epi) {
            case 0: GK_DISPATCH(true, 0); break;
            default: GK_DISPATCH(true, 1); break;
        }
    }
#undef GK_DISPATCH
}

// ================== LN over 768 + optional window partition ================
// window=0: token t reads h[t], writes y[t]  (grid = ntok)
// window=1: t indexes the padded 42x42 / 14x14-window layout (grid = 1764);
//           pad tokens get exact zeros (reference pads AFTER LN).
__global__ __launch_bounds__(256) void ln_part_k(
    const float* __restrict__ x, float* __restrict__ y,
    const float* __restrict__ w, const float* __restrict__ b, int window)
{
    __shared__ float s1[256], s2[256];
    const int t = blockIdx.x, tid = threadIdx.x;
    int g = t; bool valid = true;
    if (window) {
        const int wi = t / 196, loc = t - wi * 196;
        const int wy = wi / 3, wx = wi - wy * 3;
        const int ly = loc / 14, lx = loc - ly * 14;
        const int gy = wy * 14 + ly, gx = wx * 14 + lx;
        valid = (gy < 32) && (gx < 32);
        g = gy * 32 + gx;
    }
    float xs[3] = {0.f, 0.f, 0.f};
    if (valid) {
        const float* xr = x + (long)g * 768;
        xs[0] = xr[tid]; xs[1] = xr[tid + 256]; xs[2] = xr[tid + 512];
    }
    s1[tid] = xs[0] + xs[1] + xs[2];
    s2[tid] = xs[0] * xs[0] + xs[1] * xs[1] + xs[2] * xs[2];
    __syncthreads();
    for (int off = 128; off > 0; off >>= 1) {
        if (tid < off) { s1[tid] += s1[tid + off]; s2[tid] += s2[tid + off]; }
        __syncthreads();
    }
    const float mean = s1[0] * (1.f / 768.f);
    const float var  = s2[0] * (1.f / 768.f) - mean * mean;
    const float rs   = rsqrtf(var + 1e-6f);
    float* yr = y + (long)t * 768;
    if (valid) {
        #pragma unroll
        for (int j = 0; j < 3; ++j) {
            const int c = tid + j * 256;
            yr[c] = (xs[j] - mean) * rs * w[c] + b[c];
        }
    } else {
        #pragma unroll
        for (int j = 0; j < 3; ++j) yr[tid + j * 256] = 0.f;
    }
}

// =================== residual scatter-add (window unpartition) =============
__global__ void scatter_add_k(float* __restrict__ h, const float* __restrict__ src, int window)
{
    const int idx = blockIdx.x * 256 + threadIdx.x;
    if (idx >= 1024 * 768) return;
    const int g = idx / 768, c = idx - g * 768;
    int t = g;
    if (window) {
        const int gy = g >> 5, gx = g & 31;
        const int wy = gy / 14, ly = gy - wy * 14;
        const int wx = gx / 14, lx = gx - wx * 14;
        t = (wy * 3 + wx) * 196 + ly * 14 + lx;
    }
    h[idx] += src[(long)t * 768 + c];
}

// =================== decomposed rel-pos dot products =======================
// relh[z*S+t][kh] = sum_c q[b,t,h,c] * Rh[qh-kh+H-1][c]   (q UNSCALED)
__global__ __launch_bounds__(64) void qrel_k(
    const float* __restrict__ qkv, const float* __restrict__ Rh, const float* __restrict__ Rw,
    float* __restrict__ relh, float* __restrict__ relw, int S, int H, int nh)
{
    const int row = blockIdx.x;               // z*S + t
    const int z = row / S, t = row - z * S;
    const int b = z / nh, hh = z - b * nh;
    const int r = threadIdx.x;
    const int W = H;
    const int qh = t / W, qw = t - qh * W;
    const float* q = qkv + ((long)(b * S + t)) * 2304 + hh * 64;
    if (r < H) {
        const float* R = Rh + (long)(qh - r + H - 1) * 64;
        float s = 0.f;
        for (int c = 0; c < 64; ++c) s += q[c] * R[c];
        relh[(long)row * H + r] = s;
    } else if (r < H + W) {
        const int r2 = r - H;
        const float* R = Rw + (long)(qw - r2 + W - 1) * 64;
        float s = 0.f;
        for (int c = 0; c < 64; ++c) s += q[c] * R[c];
        relw[(long)row * W + r2] = s;
    }
}

// =================== softmax over one attn row, rel-pos fused ==============
__global__ __launch_bounds__(256) void softmax_rel_k(
    float* __restrict__ attn, const float* __restrict__ relh, const float* __restrict__ relw,
    int S, int W)
{
    __shared__ float red[256];
    const long row = blockIdx.x;
    const int H = S / W;
    float* a = attn + row * S;
    const float* rh = relh + row * H;
    const float* rw = relw + row * W;
    const int tid = threadIdx.x;

    float mx = -1e30f;
    for (int j = tid; j < S; j += 256) {
        const int kh = j / W, kw = j - kh * W;
        const float v = a[j] + rh[kh] + rw[kw];
        a[j] = v;
        mx = fmaxf(mx, v);
    }
    red[tid] = mx; __syncthreads();
    for (int off = 128; off > 0; off >>= 1) {
        if (tid < off) red[tid] = fmaxf(red[tid], red[tid + off]);
        __syncthreads();
    }
    mx = red[0];
    __syncthreads();
    float sum = 0.f;
    for (int j = tid; j < S; j += 256) {
        const float e = __expf(a[j] - mx);
        a[j] = e;
        sum += e;
    }
    red[tid] = sum; __syncthreads();
    for (int off = 128; off > 0; off >>= 1) {
        if (tid < off) red[tid] += red[tid + off];
        __syncthreads();
    }
    const float inv = 1.0f / red[0];
    for (int j = tid; j < S; j += 256) a[j] *= inv;
}

// ============================ misc small kernels ===========================
__global__ void im2col_patch_k(const float* __restrict__ x, float* __restrict__ xc)
{
    const int idx = blockIdx.x * 256 + threadIdx.x;
    if (idx >= 1024 * 768) return;
    const int t = idx / 768, k = idx - t * 768;
    const int ph = t >> 5, pw = t & 31;
    const int c = k >> 8, rem = k & 255;
    const int kh = rem >> 4, kw = rem & 15;
    xc[idx] = x[((long)c * 512 + (ph * 16 + kh)) * 512 + (pw * 16 + kw)];
}

__global__ void add_pos_k(float* __restrict__ h, const float* __restrict__ pos)
{
    const int idx = blockIdx.x * 256 + threadIdx.x;
    if (idx < 1024 * 768) h[idx] += pos[idx];
}

__global__ void im2col_neck_k(const float* __restrict__ in, float* __restrict__ xc)
{
    const int idx = blockIdx.x * 256 + threadIdx.x;
    if (idx >= 1024 * 2304) return;
    const int p = idx / 2304, k = idx - p * 2304;
    const int ci = k / 9, r = k - ci * 9;
    const int kh = r / 3, kw = r - kh * 3;
    const int gy = (p >> 5) + kh - 1, gx = (p & 31) + kw - 1;
    float v = 0.f;
    if (gy >= 0 && gy < 32 && gx >= 0 && gx < 32)
        v = in[((long)(gy * 32 + gx)) * 256 + ci];
    xc[idx] = v;
}

// channels-last LN over 256 channels per spatial position (SAM LayerNorm2d)
__global__ __launch_bounds__(256) void ln2d_k(
    const float* __restrict__ x, float* __restrict__ y,
    const float* __restrict__ w, const float* __restrict__ b, int chw_out)
{
    __shared__ float s1[256], s2[256];
    const int p = blockIdx.x, c = threadIdx.x;
    const float v = x[(long)p * 256 + c];
    s1[c] = v; s2[c] = v * v;
    __syncthreads();
    for (int off = 128; off > 0; off >>= 1) {
        if (c < off) { s1[c] += s1[c + off]; s2[c] += s2[c + off]; }
        __syncthreads();
    }
    const float mean = s1[0] * (1.f / 256.f);
    const float var  = s2[0] * (1.f / 256.f) - mean * mean;
    const float out  = (v - mean) * rsqrtf(var + 1e-6f) * w[c] + b[c];
    if (chw_out) y[(long)c * 1024 + p] = out;
    else         y[(long)p * 256 + c] = out;
}

// =============================== driver ====================================
extern "C" void kernel_launch(void* const* d_in, const int* in_sizes, int n_in,
                              void* d_out, int out_size, void* d_ws, size_t ws_size,
                              hipStream_t stream)
{
    const float* x       = (const float*)d_in[0];
    const float* patch_w = (const float*)d_in[1];
    const float* patch_b = (const float*)d_in[2];
    const float* pos     = (const float*)d_in[3];
    const float* ln1_w   = (const float*)d_in[4];
    const float* ln1_b   = (const float*)d_in[5];
    const float* qkv_w   = (const float*)d_in[6];
    const float* qkv_b   = (const float*)d_in[7];
    const float* proj_w  = (const float*)d_in[8];
    const float* proj_b  = (const float*)d_in[9];
    const float* ln2_w   = (const float*)d_in[10];
    const float* ln2_b   = (const float*)d_in[11];
    const float* mlp1_w  = (const float*)d_in[12];
    const float* mlp1_b  = (const float*)d_in[13];
    const float* mlp2_w  = (const float*)d_in[14];
    const float* mlp2_b  = (const float*)d_in[15];
    const float* rhw     = (const float*)d_in[16];
    const float* rww     = (const float*)d_in[17];
    const float* rhg     = (const float*)d_in[18];
    const float* rwg     = (const float*)d_in[19];
    const float* neck_w1 = (const float*)d_in[20];
    const float* nln1_w  = (const float*)d_in[21];
    const float* nln1_b  = (const float*)d_in[22];
    const float* neck_w2 = (const float*)d_in[23];
    const float* nln2_w  = (const float*)d_in[24];
    const float* nln2_b  = (const float*)d_in[25];

    float* ws   = (float*)d_ws;
    float* h    = ws;                 // 1024*768           =   786432
    float* y    = h + 786432;         // 1764*768           =  1354752
    float* qkvb = y + 1354752;        // 1764*2304          =  4064256
    float* attn = qkvb + 4064256;     // 12*1024*1024       = 12582912
    float* o    = attn + 12582912;    // 1764*768           =  1354752
    float* tb   = o + 1354752;        // 1024*3072          =  3145728
    float* relh = tb + 3145728;       // 12*1024*32         =   393216
    float* relw = relh + 393216;      //                    =   393216
    (void)ws_size; (void)in_sizes; (void)n_in; (void)out_size;

    // ---- patch embed: im2col + GEMM(B^T) + bias, then + pos_embed ----
    im2col_patch_k<<<CDIV(786432, 256), 256, 0, stream>>>(x, qkvb);
    gemm(stream, true, 1, qkvb, 768, patch_w, 768, h, 768, patch_b,
         1024, 768, 768, 1.f, 1, 1, 0, 0, 0, 0, 0, 0);
    add_pos_k<<<CDIV(786432, 256), 256, 0, stream>>>(h, pos);

    int wi = 0, gi = 0;
    for (int i = 0; i < 12; ++i) {
        const bool glb = (i == 2) || (i == 5) || (i == 8) || (i == 11);
        const int S  = glb ? 1024 : 196;
        const int nB = glb ? 1 : 9;
        const int ntok = nB * S;
        const int HH = glb ? 32 : 14;
        const int Z  = nB * 12;

        // LN1 (+ window partition with zero pad)
        ln_part_k<<<ntok, 256, 0, stream>>>(h, y, ln1_w + i * 768, ln1_b + i * 768, glb ? 0 : 1);
        // QKV
        gemm(stream, false, 1, y, 768, qkv_w + (long)i * 768 * 2304, 2304, qkvb, 2304,
             qkv_b + i * 2304, ntok, 2304, 768, 1.f, 1, 1, 0, 0, 0, 0, 0, 0);
        // QK^T (batched over windows x heads), alpha = head_dim^-0.5
        gemm(stream, true, 0, qkvb, 2304, qkvb + 768, 2304, attn, S, nullptr,
             S, S, 64, 0.125f, Z, 12,
             (long)S * 2304, 64, (long)S * 2304, 64, (long)12 * S * S, (long)S * S);
        // rel-pos dots (unscaled q)
        const float* Rh = glb ? (rhg + (long)gi * 63 * 64) : (rhw + (long)wi * 27 * 64);
        const float* Rw = glb ? (rwg + (long)gi * 63 * 64) : (rww + (long)wi * 27 * 64);
        qrel_k<<<Z * S, 64, 0, stream>>>(qkvb, Rh, Rw, relh, relw, S, HH, 12);
        // softmax with rel-pos added in-pass
        softmax_rel_k<<<Z * S, 256, 0, stream>>>(attn, relh, relw, S, HH);
        // P @ V, heads scattered into token-major (ntok x 768)
        gemm(stream, false, 0, attn, S, qkvb + 1536, 2304, o, 768, nullptr,
             S, 64, S, 1.f, Z, 12,
             (long)12 * S * S, (long)S * S, (long)S * 2304, 64, (long)S * 768, 64);
        // proj + bias
        gemm(stream, false, 1, o, 768, proj_w + (long)i * 768 * 768, 768, tb, 768,
             proj_b + i * 768, ntok, 768, 768, 1.f, 1, 1, 0, 0, 0, 0, 0, 0);
        // residual (window unpartition crop)
        scatter_add_k<<<CDIV(786432, 256), 256, 0, stream>>>(h, tb, glb ? 0 : 1);
        // MLP
        ln_part_k<<<1024, 256, 0, stream>>>(h, y, ln2_w + i * 768, ln2_b + i * 768, 0);
        gemm(stream, false, 2, y, 768, mlp1_w + (long)i * 768 * 3072, 3072, tb, 3072,
             mlp1_b + i * 3072, 1024, 3072, 768, 1.f, 1, 1, 0, 0, 0, 0, 0, 0);
        gemm(stream, false, 3, tb, 3072, mlp2_w + (long)i * 3072 * 768, 768, h, 768,
             mlp2_b + i * 768, 1024, 768, 3072, 1.f, 1, 1, 0, 0, 0, 0, 0, 0);

        if (glb) gi++; else wi++;
    }

    // ---- neck ----
    gemm(stream, true, 0, h, 768, neck_w1, 768, y, 256, nullptr,
         1024, 256, 768, 1.f, 1, 1, 0, 0, 0, 0, 0, 0);
    ln2d_k<<<1024, 256, 0, stream>>>(y, o, nln1_w, nln1_b, 0);
    im2col_neck_k<<<CDIV(1024 * 2304, 256), 256, 0, stream>>>(o, qkvb);
    gemm(stream, true, 0, qkvb, 2304, neck_w2, 2304, y, 256, nullptr,
         1024, 256, 2304, 1.f, 1, 1, 0, 0, 0, 0, 0, 0);
    ln2d_k<<<1024, 256, 0, stream>>>(y, (float*)d_out, nln2_w, nln2_b, 1);
}

// Round 3
// 4020.018 us; speedup vs baseline: 1.9696x; 1.9696x over previous
//
#include <hip/hip_runtime.h>
#include <hip/hip_bf16.h>
#include <math.h>

#define CDIV(a,b) (((a)+(b)-1)/(b))

typedef short bf16x8 __attribute__((ext_vector_type(8)));
typedef float f32x4 __attribute__((ext_vector_type(4)));

__device__ __forceinline__ ushort f2bf(float f){
    __hip_bfloat16 h = __float2bfloat16(f);
    return *reinterpret_cast<ushort*>(&h);
}
__device__ __forceinline__ float bf2f(ushort u){
    __hip_bfloat16 h;
    *reinterpret_cast<ushort*>(&h) = u;
    return __bfloat162float(h);
}

// ====================== bf16 MFMA GEMM =====================================
// C[M,N] = alpha * A[M,K](bf16,row-major) @ B[N,K](bf16,row-major)^T
// EPI: 0 none | 1 +bias | 2 +bias,gelu | 3 +bias,+res (fp32 residual)
// OUTBF: write bf16 instead of fp32.
// batched via gridDim.z: z -> (bb=z/nh, hh=z%nh), element strides.
// K must be a multiple of 32. Tiles: BM=128, BN=64, BK=32, 4 waves (2x2).
template<int EPI, bool OUTBF>
__global__ __launch_bounds__(256) void mgemm_k(
    const ushort* __restrict__ A, int lda,
    const ushort* __restrict__ B, int ldb,
    void* __restrict__ Cv, int ldc,
    const float* __restrict__ bias, const float* __restrict__ res,
    int M, int N, int K, float alpha, int nh,
    long sAb, long sAh, long sBb, long sBh, long sCb, long sCh)
{
    const int z = blockIdx.z;
    const int bb = z / nh, hh = z - bb * nh;
    A += bb * sAb + hh * sAh;
    B += bb * sBb + hh * sBh;
    const long coff = bb * sCb + hh * sCh;

    __shared__ __align__(16) char smem[12288];
    char* sA = smem;            // 4 kgroups x 128 rows x 16B, XOR-swizzled
    char* sB = smem + 8192;     // 4 kgroups x  64 cols x 16B

    const int tid = threadIdx.x;
    const int m0 = blockIdx.y * 128;
    const int n0 = blockIdx.x * 64;
    const int lane = tid & 63;
    const int w = tid >> 6;
    const int wr = w >> 1, wc = w & 1;   // wave grid 2(M) x 2(N)
    const int kg = lane >> 4, lr = lane & 15;

    const bf16x8 z8 = {0,0,0,0,0,0,0,0};
    f32x4 acc[4][2];
    #pragma unroll
    for (int mi = 0; mi < 4; ++mi)
        #pragma unroll
        for (int ni = 0; ni < 2; ++ni)
            acc[mi][ni] = (f32x4){0.f, 0.f, 0.f, 0.f};

    for (int k0 = 0; k0 < K; k0 += 32) {
        // ---- stage A: 128 rows x 32 k = 512 x 16B chunks ----
        #pragma unroll
        for (int it = 0; it < 2; ++it) {
            const int c = tid + (it << 8);
            const int r = c >> 2, g = c & 3;
            const int gm = m0 + r;
            bf16x8 v = z8;
            if (gm < M) v = *(const bf16x8*)(A + (long)gm * lda + k0 + (g << 3));
            *(bf16x8*)(sA + (g << 11) + (((r << 4)) ^ (g << 5))) = v;
        }
        // ---- stage B: 64 cols x 32 k = 256 x 16B chunks ----
        {
            const int n = tid >> 2, g = tid & 3;
            const int gn = n0 + n;
            bf16x8 v = z8;
            if (gn < N) v = *(const bf16x8*)(B + (long)gn * ldb + k0 + (g << 3));
            *(bf16x8*)(sB + (g << 10) + (((n << 4)) ^ (g << 5))) = v;
        }
        __syncthreads();

        bf16x8 af[4], bq[2];
        #pragma unroll
        for (int mi = 0; mi < 4; ++mi)
            af[mi] = *(const bf16x8*)(sA + (kg << 11) +
                     ((((wr * 64 + mi * 16 + lr) << 4)) ^ (kg << 5)));
        #pragma unroll
        for (int ni = 0; ni < 2; ++ni)
            bq[ni] = *(const bf16x8*)(sB + (kg << 10) +
                     ((((wc * 32 + ni * 16 + lr) << 4)) ^ (kg << 5)));
        #pragma unroll
        for (int mi = 0; mi < 4; ++mi)
            #pragma unroll
            for (int ni = 0; ni < 2; ++ni)
                acc[mi][ni] = __builtin_amdgcn_mfma_f32_16x16x32_bf16(
                    af[mi], bq[ni], acc[mi][ni], 0, 0, 0);
        __syncthreads();
    }

    // ---- epilogue: D row=(lane>>4)*4+q, col=lane&15 (m89-verified) ----
    #pragma unroll
    for (int mi = 0; mi < 4; ++mi) {
        #pragma unroll
        for (int ni = 0; ni < 2; ++ni) {
            #pragma unroll
            for (int q = 0; q < 4; ++q) {
                const int gm = m0 + wr * 64 + mi * 16 + kg * 4 + q;
                const int gn = n0 + wc * 32 + ni * 16 + lr;
                if (gm < M && gn < N) {
                    float v = acc[mi][ni][q] * alpha;
                    if (EPI >= 1) v += bias[gn];
                    const long ci = coff + (long)gm * ldc + gn;
                    if (EPI == 2) v = 0.5f * v * (1.0f + erff(v * 0.70710678118654752f));
                    if (EPI == 3) v += res[ci];
                    if (OUTBF) ((ushort*)Cv)[ci] = f2bf(v);
                    else       ((float*)Cv)[ci]  = v;
                }
            }
        }
    }
}

static inline void mgemm(hipStream_t st, int epi, bool outbf,
                         const ushort* A, int lda, const ushort* B, int ldb,
                         void* C, int ldc, const float* bias, const float* res,
                         int M, int N, int K, float alpha,
                         int batch, int nh,
                         long sAb, long sAh, long sBb, long sBh, long sCb, long sCh)
{
    dim3 g(CDIV(N, 64), CDIV(M, 128), batch);
    dim3 b(256);
#define MG(E, O) mgemm_k<E, O><<<g, b, 0, st>>>(A, lda, B, ldb, C, ldc, bias, res, M, N, K, alpha, nh, sAb, sAh, sBb, sBh, sCb, sCh)
    if (epi == 0)              MG(0, false);
    else if (epi == 1 && !outbf) MG(1, false);
    else if (epi == 1 &&  outbf) MG(1, true);
    else if (epi == 2)         MG(2, true);
    else                       MG(3, false);
#undef MG
}

// ============== fp32 [K][N] -> bf16 [N][K] transpose (32x32 tiles) =========
__global__ __launch_bounds__(256) void wtrans_k(
    const float* __restrict__ in, ushort* __restrict__ out, int K, int N)
{
    __shared__ float t[32][33];
    const int k0 = blockIdx.y << 5, n0 = blockIdx.x << 5;
    const int tx = threadIdx.x, ty = threadIdx.y;
    #pragma unroll
    for (int j = 0; j < 32; j += 8)
        t[ty + j][tx] = in[(long)(k0 + ty + j) * N + n0 + tx];
    __syncthreads();
    #pragma unroll
    for (int j = 0; j < 32; j += 8)
        out[(long)(n0 + ty + j) * K + k0 + tx] = f2bf(t[tx][ty + j]);
}

// ===================== fp32 -> bf16 elementwise ============================
__global__ void cvt_k(const float* __restrict__ in, ushort* __restrict__ out, int n)
{
    const int i = blockIdx.x * 256 + threadIdx.x;
    if (i < n) out[i] = f2bf(in[i]);
}

// ====== LN over 768 (+optional window partition), bf16 output =============
__global__ __launch_bounds__(256) void ln_part_k(
    const float* __restrict__ x, ushort* __restrict__ y,
    const float* __restrict__ w, const float* __restrict__ b, int window)
{
    __shared__ float s1[256], s2[256];
    const int t = blockIdx.x, tid = threadIdx.x;
    int g = t; bool valid = true;
    if (window) {
        const int wi = t / 196, loc = t - wi * 196;
        const int wy = wi / 3, wx = wi - wy * 3;
        const int ly = loc / 14, lx = loc - ly * 14;
        const int gy = wy * 14 + ly, gx = wx * 14 + lx;
        valid = (gy < 32) && (gx < 32);
        g = gy * 32 + gx;
    }
    float xs[3] = {0.f, 0.f, 0.f};
    if (valid) {
        const float* xr = x + (long)g * 768;
        xs[0] = xr[tid]; xs[1] = xr[tid + 256]; xs[2] = xr[tid + 512];
    }
    s1[tid] = xs[0] + xs[1] + xs[2];
    s2[tid] = xs[0] * xs[0] + xs[1] * xs[1] + xs[2] * xs[2];
    __syncthreads();
    for (int off = 128; off > 0; off >>= 1) {
        if (tid < off) { s1[tid] += s1[tid + off]; s2[tid] += s2[tid + off]; }
        __syncthreads();
    }
    const float mean = s1[0] * (1.f / 768.f);
    const float var  = s2[0] * (1.f / 768.f) - mean * mean;
    const float rs   = rsqrtf(var + 1e-6f);
    ushort* yr = y + (long)t * 768;
    if (valid) {
        #pragma unroll
        for (int j = 0; j < 3; ++j) {
            const int c = tid + j * 256;
            yr[c] = f2bf((xs[j] - mean) * rs * w[c] + b[c]);
        }
    } else {
        #pragma unroll
        for (int j = 0; j < 3; ++j) yr[tid + j * 256] = 0;
    }
}

// ============ residual scatter-add (window unpartition crop) ===============
__global__ void scatter_add_k(float* __restrict__ h, const float* __restrict__ src, int window)
{
    const int idx = blockIdx.x * 256 + threadIdx.x;
    if (idx >= 1024 * 768) return;
    const int g = idx / 768, c = idx - g * 768;
    int t = g;
    if (window) {
        const int gy = g >> 5, gx = g & 31;
        const int wy = gy / 14, ly = gy - wy * 14;
        const int wx = gx / 14, lx = gx - wx * 14;
        t = (wy * 3 + wx) * 196 + ly * 14 + lx;
    }
    h[idx] += src[(long)t * 768 + c];
}

// ================== decomposed rel-pos dots (bf16 q) =======================
__global__ __launch_bounds__(64) void qrel_k(
    const ushort* __restrict__ qkv, const float* __restrict__ Rh, const float* __restrict__ Rw,
    float* __restrict__ relh, float* __restrict__ relw, int S, int H, int nh)
{
    const int row = blockIdx.x;               // z*S + t
    const int z = row / S, t = row - z * S;
    const int b = z / nh, hh = z - b * nh;
    const int r = threadIdx.x;
    const int W = H;
    const int qh = t / W, qw = t - qh * W;
    const ushort* q = qkv + ((long)(b * S + t)) * 2304 + hh * 64;
    if (r < H) {
        const float* R = Rh + (long)(qh - r + H - 1) * 64;
        float s = 0.f;
        for (int c = 0; c < 64; ++c) s += bf2f(q[c]) * R[c];
        relh[(long)row * H + r] = s;
    } else if (r < H + W) {
        const int r2 = r - H;
        const float* R = Rw + (long)(qw - r2 + W - 1) * 64;
        float s = 0.f;
        for (int c = 0; c < 64; ++c) s += bf2f(q[c]) * R[c];
        relw[(long)row * W + r2] = s;
    }
}

// ===== softmax (fp32 logits + rel) -> bf16 probs, zero-padded to Spad ======
__global__ __launch_bounds__(256) void softmax_rel_k(
    const float* __restrict__ attn, ushort* __restrict__ probs,
    const float* __restrict__ relh, const float* __restrict__ relw,
    int S, int W, int Spad)
{
    __shared__ float red[256];
    const long row = blockIdx.x;
    const int H = S / W;
    const float* a = attn + row * S;
    const int zz = (int)(row / S), t = (int)(row - (long)zz * S);
    ushort* p = probs + (long)zz * S * Spad + (long)t * Spad;
    const float* rh = relh + row * H;
    const float* rw = relw + row * W;
    const int tid = threadIdx.x;

    float vv[4];
    float mx = -1e30f;
    #pragma unroll
    for (int i = 0; i < 4; ++i) {
        const int j = tid + (i << 8);
        float v = -1e30f;
        if (j < S) {
            const int kh = j / W, kw = j - kh * W;
            v = a[j] + rh[kh] + rw[kw];
        }
        vv[i] = v;
        mx = fmaxf(mx, v);
    }
    red[tid] = mx; __syncthreads();
    for (int off = 128; off > 0; off >>= 1) {
        if (tid < off) red[tid] = fmaxf(red[tid], red[tid + off]);
        __syncthreads();
    }
    mx = red[0]; __syncthreads();
    float sum = 0.f;
    #pragma unroll
    for (int i = 0; i < 4; ++i) {
        const int j = tid + (i << 8);
        if (j < S) { const float e = __expf(vv[i] - mx); vv[i] = e; sum += e; }
    }
    red[tid] = sum; __syncthreads();
    for (int off = 128; off > 0; off >>= 1) {
        if (tid < off) red[tid] += red[tid + off];
        __syncthreads();
    }
    const float inv = 1.0f / red[0];
    #pragma unroll
    for (int i = 0; i < 4; ++i) {
        const int j = tid + (i << 8);
        if (j < S) p[j] = f2bf(vv[i] * inv);
    }
    for (int j = S + tid; j < Spad; j += 256) p[j] = 0;
}

// ===== v transpose: qkv v-part -> vT[z][64][Spad] bf16 (pad zeros) =========
__global__ void vT_k(const ushort* __restrict__ qkv, ushort* __restrict__ vT,
                     int S, int Spad, int total)
{
    const int idx = blockIdx.x * 256 + threadIdx.x;
    if (idx >= total) return;
    const int z = idx / (64 * Spad);
    const int rem = idx - z * 64 * Spad;
    const int c = rem / Spad, t = rem - c * Spad;
    const int bb = z / 12, hh = z - bb * 12;
    ushort v = 0;
    if (t < S) v = qkv[((long)(bb * S + t)) * 2304 + 1536 + hh * 64 + c];
    vT[idx] = v;
}

// ============================ misc =========================================
__global__ void im2col_patch_k(const float* __restrict__ x, ushort* __restrict__ xc)
{
    const int idx = blockIdx.x * 256 + threadIdx.x;
    if (idx >= 1024 * 768) return;
    const int t = idx / 768, k = idx - t * 768;
    const int ph = t >> 5, pw = t & 31;
    const int c = k >> 8, rem = k & 255;
    const int kh = rem >> 4, kw = rem & 15;
    xc[idx] = f2bf(x[((long)c * 512 + (ph * 16 + kh)) * 512 + (pw * 16 + kw)]);
}

__global__ void add_pos_k(float* __restrict__ h, const float* __restrict__ pos)
{
    const int idx = blockIdx.x * 256 + threadIdx.x;
    if (idx < 1024 * 768) h[idx] += pos[idx];
}

__global__ void im2col_neck_k(const float* __restrict__ in, ushort* __restrict__ xc)
{
    const int idx = blockIdx.x * 256 + threadIdx.x;
    if (idx >= 1024 * 2304) return;
    const int p = idx / 2304, k = idx - p * 2304;
    const int ci = k / 9, r = k - ci * 9;
    const int kh = r / 3, kw = r - kh * 3;
    const int gy = (p >> 5) + kh - 1, gx = (p & 31) + kw - 1;
    float v = 0.f;
    if (gy >= 0 && gy < 32 && gx >= 0 && gx < 32)
        v = in[((long)(gy * 32 + gx)) * 256 + ci];
    xc[idx] = f2bf(v);
}

__global__ __launch_bounds__(256) void ln2d_k(
    const float* __restrict__ x, float* __restrict__ y,
    const float* __restrict__ w, const float* __restrict__ b, int chw_out)
{
    __shared__ float s1[256], s2[256];
    const int p = blockIdx.x, c = threadIdx.x;
    const float v = x[(long)p * 256 + c];
    s1[c] = v; s2[c] = v * v;
    __syncthreads();
    for (int off = 128; off > 0; off >>= 1) {
        if (c < off) { s1[c] += s1[c + off]; s2[c] += s2[c + off]; }
        __syncthreads();
    }
    const float mean = s1[0] * (1.f / 256.f);
    const float var  = s2[0] * (1.f / 256.f) - mean * mean;
    const float out  = (v - mean) * rsqrtf(var + 1e-6f) * w[c] + b[c];
    if (chw_out) y[(long)c * 1024 + p] = out;
    else         y[(long)p * 256 + c] = out;
}

// =============================== driver ====================================
extern "C" void kernel_launch(void* const* d_in, const int* in_sizes, int n_in,
                              void* d_out, int out_size, void* d_ws, size_t ws_size,
                              hipStream_t stream)
{
    const float* x       = (const float*)d_in[0];
    const float* patch_w = (const float*)d_in[1];
    const float* patch_b = (const float*)d_in[2];
    const float* pos     = (const float*)d_in[3];
    const float* ln1_w   = (const float*)d_in[4];
    const float* ln1_b   = (const float*)d_in[5];
    const float* qkv_w   = (const float*)d_in[6];
    const float* qkv_b   = (const float*)d_in[7];
    const float* proj_w  = (const float*)d_in[8];
    const float* proj_b  = (const float*)d_in[9];
    const float* ln2_w   = (const float*)d_in[10];
    const float* ln2_b   = (const float*)d_in[11];
    const float* mlp1_w  = (const float*)d_in[12];
    const float* mlp1_b  = (const float*)d_in[13];
    const float* mlp2_w  = (const float*)d_in[14];
    const float* mlp2_b  = (const float*)d_in[15];
    const float* rhw     = (const float*)d_in[16];
    const float* rww     = (const float*)d_in[17];
    const float* rhg     = (const float*)d_in[18];
    const float* rwg     = (const float*)d_in[19];
    const float* neck_w1 = (const float*)d_in[20];
    const float* nln1_w  = (const float*)d_in[21];
    const float* nln1_b  = (const float*)d_in[22];
    const float* neck_w2 = (const float*)d_in[23];
    const float* nln2_w  = (const float*)d_in[24];
    const float* nln2_b  = (const float*)d_in[25];
    (void)in_sizes; (void)n_in; (void)out_size; (void)ws_size;

    char* cur = (char*)d_ws;
    auto alloc = [&](size_t bytes) -> char* {
        char* p = cur; cur += (bytes + 255) & ~(size_t)255; return p;
    };
    float*  h      = (float*) alloc(1024l * 768 * 4);
    ushort* ybf    = (ushort*)alloc(1764l * 768 * 2);
    ushort* qkvbf  = (ushort*)alloc(1764l * 2304 * 2);
    float*  attn   = (float*) alloc(12l * 1024 * 1024 * 4);
    ushort* probs  = (ushort*)alloc(12l * 1024 * 1024 * 2);
    float*  o      = (float*) alloc(1764l * 768 * 4);
    ushort* obf    = (ushort*)alloc(1764l * 768 * 2);
    float*  tb     = (float*) alloc(1024l * 3072 * 4);
    float*  relh   = (float*) alloc(12l * 1024 * 32 * 4);
    float*  relw   = (float*) alloc(12l * 1024 * 32 * 4);
    ushort* vT     = (ushort*)alloc(108l * 64 * 224 * 2);
    ushort* qkvT   = (ushort*)alloc(2304l * 768 * 2);
    ushort* projT  = (ushort*)alloc(768l * 768 * 2);
    ushort* m1T    = (ushort*)alloc(3072l * 768 * 2);
    ushort* m2T    = (ushort*)alloc(768l * 3072 * 2);
    ushort* patchbf= (ushort*)alloc(768l * 768 * 2);
    ushort* xc     = (ushort*)alloc(1024l * 768 * 2);
    ushort* xcn    = (ushort*)alloc(1024l * 2304 * 2);
    ushort* hbf    = (ushort*)alloc(1024l * 768 * 2);
    ushort* nw1bf  = (ushort*)alloc(256l * 768 * 2);
    ushort* nw2bf  = (ushort*)alloc(256l * 2304 * 2);
    float*  nk1    = (float*) alloc(1024l * 256 * 4);
    float*  nk2    = (float*) alloc(1024l * 256 * 4);

    // ---- one-time weight converts (already [N][K] layouts) ----
    cvt_k<<<CDIV(768 * 768, 256), 256, 0, stream>>>(patch_w, patchbf, 768 * 768);
    cvt_k<<<CDIV(256 * 768, 256), 256, 0, stream>>>(neck_w1, nw1bf, 256 * 768);
    cvt_k<<<CDIV(256 * 2304, 256), 256, 0, stream>>>(neck_w2, nw2bf, 256 * 2304);

    // ---- patch embed ----
    im2col_patch_k<<<CDIV(786432, 256), 256, 0, stream>>>(x, xc);
    mgemm(stream, 1, false, xc, 768, patchbf, 768, h, 768, patch_b, nullptr,
          1024, 768, 768, 1.f, 1, 1, 0, 0, 0, 0, 0, 0);
    add_pos_k<<<CDIV(786432, 256), 256, 0, stream>>>(h, pos);

    int wi = 0, gi = 0;
    for (int i = 0; i < 12; ++i) {
        const bool glb = (i == 2) || (i == 5) || (i == 8) || (i == 11);
        const int S  = glb ? 1024 : 196;
        const int Spad = glb ? 1024 : 224;
        const int nB = glb ? 1 : 9;
        const int ntok = nB * S;
        const int HH = glb ? 32 : 14;
        const int Z  = nB * 12;

        // per-layer weight transposes [K][N] -> bf16 [N][K]
        wtrans_k<<<dim3(2304/32, 768/32),  dim3(32,8), 0, stream>>>(qkv_w  + (long)i*768*2304, qkvT, 768, 2304);
        wtrans_k<<<dim3(768/32,  768/32),  dim3(32,8), 0, stream>>>(proj_w + (long)i*768*768,  projT, 768, 768);
        wtrans_k<<<dim3(3072/32, 768/32),  dim3(32,8), 0, stream>>>(mlp1_w + (long)i*768*3072, m1T,  768, 3072);
        wtrans_k<<<dim3(768/32,  3072/32), dim3(32,8), 0, stream>>>(mlp2_w + (long)i*3072*768, m2T, 3072, 768);

        // LN1 (+window partition, zero pad) -> bf16
        ln_part_k<<<ntok, 256, 0, stream>>>(h, ybf, ln1_w + i*768, ln1_b + i*768, glb ? 0 : 1);
        // QKV -> bf16
        mgemm(stream, 1, true, ybf, 768, qkvT, 768, qkvbf, 2304, qkv_b + i*2304, nullptr,
              ntok, 2304, 768, 1.f, 1, 1, 0, 0, 0, 0, 0, 0);
        // QK^T (alpha = 1/8) -> fp32 logits
        mgemm(stream, 0, false, qkvbf, 2304, qkvbf + 768, 2304, attn, S, nullptr, nullptr,
              S, S, 64, 0.125f, Z, 12,
              (long)S * 2304, 64, (long)S * 2304, 64, (long)12 * S * S, (long)S * S);
        // rel-pos dots (unscaled q)
        const float* Rh = glb ? (rhg + (long)gi * 63 * 64) : (rhw + (long)wi * 27 * 64);
        const float* Rw = glb ? (rwg + (long)gi * 63 * 64) : (rww + (long)wi * 27 * 64);
        qrel_k<<<Z * S, 64, 0, stream>>>(qkvbf, Rh, Rw, relh, relw, S, HH, 12);
        // v transpose -> vT[z][64][Spad]
        {
            const int tot = Z * 64 * Spad;
            vT_k<<<CDIV(tot, 256), 256, 0, stream>>>(qkvbf, vT, S, Spad, tot);
        }
        // softmax + rel -> bf16 probs (padded)
        softmax_rel_k<<<Z * S, 256, 0, stream>>>(attn, probs, relh, relw, S, HH, Spad);
        // P @ V -> o (fp32, heads scattered token-major)
        mgemm(stream, 0, false, probs, Spad, vT, Spad, o, 768, nullptr, nullptr,
              S, 64, Spad, 1.f, Z, 12,
              (long)12 * S * Spad, (long)S * Spad, (long)12 * 64 * Spad, (long)64 * Spad,
              (long)S * 768, 64);
        // proj
        cvt_k<<<CDIV(ntok * 768, 256), 256, 0, stream>>>(o, obf, ntok * 768);
        mgemm(stream, 1, false, obf, 768, projT, 768, tb, 768, proj_b + i*768, nullptr,
              ntok, 768, 768, 1.f, 1, 1, 0, 0, 0, 0, 0, 0);
        // residual (window unpartition crop)
        scatter_add_k<<<CDIV(786432, 256), 256, 0, stream>>>(h, tb, glb ? 0 : 1);
        // MLP
        ln_part_k<<<1024, 256, 0, stream>>>(h, ybf, ln2_w + i*768, ln2_b + i*768, 0);
        mgemm(stream, 2, true, ybf, 768, m1T, 768, tb, 3072, mlp1_b + i*3072, nullptr,
              1024, 3072, 768, 1.f, 1, 1, 0, 0, 0, 0, 0, 0);
        mgemm(stream, 3, false, (ushort*)tb, 3072, m2T, 3072, h, 768, mlp2_b + i*768, h,
              1024, 768, 3072, 1.f, 1, 1, 0, 0, 0, 0, 0, 0);

        if (glb) gi++; else wi++;
    }

    // ---- neck ----
    cvt_k<<<CDIV(786432, 256), 256, 0, stream>>>(h, hbf, 786432);
    mgemm(stream, 0, false, hbf, 768, nw1bf, 768, nk1, 256, nullptr, nullptr,
          1024, 256, 768, 1.f, 1, 1, 0, 0, 0, 0, 0, 0);
    ln2d_k<<<1024, 256, 0, stream>>>(nk1, nk2, nln1_w, nln1_b, 0);
    im2col_neck_k<<<CDIV(1024 * 2304, 256), 256, 0, stream>>>(nk2, xcn);
    mgemm(stream, 0, false, xcn, 2304, nw2bf, 2304, nk1, 256, nullptr, nullptr,
          1024, 256, 2304, 1.f, 1, 1, 0, 0, 0, 0, 0, 0);
    ln2d_k<<<1024, 256, 0, stream>>>(nk1, (float*)d_out, nln2_w, nln2_b, 1);
}

// Round 5
// 2953.744 us; speedup vs baseline: 2.6806x; 1.3610x over previous
//
#include <hip/hip_runtime.h>
#include <hip/hip_bf16.h>
#include <math.h>

#define CDIV(a,b) (((a)+(b)-1)/(b))

typedef short bf16x8 __attribute__((ext_vector_type(8)));
typedef float f32x4 __attribute__((ext_vector_type(4)));

__device__ __forceinline__ ushort f2bf(float f){
    __hip_bfloat16 h = __float2bfloat16(f);
    return *reinterpret_cast<ushort*>(&h);
}
__device__ __forceinline__ float bf2f(ushort u){
    __hip_bfloat16 h;
    *reinterpret_cast<ushort*>(&h) = u;
    return __bfloat162float(h);
}

// ====================== bf16 MFMA GEMM (pipelined, dbuf) ===================
// C[M,N] = alpha * A[M,K](bf16 rm) @ B[N,K](bf16 rm)^T
// EPI: 0 none | 1 +bias | 2 +bias,gelu | 3 +bias,+res(fp32)
// BM in {64,128}; BN=64; BK=32; 4 waves (2x2).
// Double-buffered LDS; reg-staged prefetch of tile t+1 overlaps compute of t;
// single barrier per K-iter. K % 32 == 0.
template<int BM, int EPI, bool OUTBF>
__global__ __launch_bounds__(256) void mgemm_k(
    const ushort* __restrict__ A, int lda,
    const ushort* __restrict__ B, int ldb,
    void* __restrict__ Cv, int ldc,
    const float* __restrict__ bias, const float* __restrict__ res,
    int M, int N, int K, float alpha, int nh,
    long sAb, long sAh, long sBb, long sBh, long sCb, long sCh)
{
    constexpr int MI = BM / 32;        // M-frags per wave (16-row frags)
    constexpr int ACH = BM / 64;       // A 16B-chunks per thread
    constexpr int ABYTES = BM * 64;    // A tile bytes (BM x 32k x 2B)
    constexpr int DBOF = ABYTES + 4096;

    const int z = blockIdx.z;
    const int bb = z / nh, hh = z - bb * nh;
    A += bb * sAb + hh * sAh;
    B += bb * sBb + hh * sBh;
    const long coff = bb * sCb + hh * sCh;

    __shared__ __align__(16) char smem[2 * DBOF];

    const int tid = threadIdx.x;
    const int m0 = blockIdx.y * BM;
    const int n0 = blockIdx.x * 64;
    const int lane = tid & 63;
    const int w = tid >> 6;
    const int wr = w >> 1, wc = w & 1;   // wave grid 2(M) x 2(N)
    const int kg = lane >> 4, lr = lane & 15;

    // ---- staging maps (constant per thread) ----
    const int rA = tid >> 2, gA = tid & 3;
    const ushort* aptr[ACH]; bool pAv[ACH]; int sAoff[ACH];
    #pragma unroll
    for (int it = 0; it < ACH; ++it) {
        const int gm = m0 + rA + it * 64;
        pAv[it] = gm < M;
        const int cm = pAv[it] ? gm : (M > 0 ? M - 1 : 0);
        aptr[it] = A + (long)cm * lda + (gA << 3);
        sAoff[it] = gA * (BM * 16) + ((rA << 4) ^ (gA << 5)) + it * 1024;
    }
    const int gn_s = n0 + rA;
    const bool pBv = gn_s < N;
    const ushort* bptr = B + (long)(pBv ? gn_s : (N - 1)) * ldb + (gA << 3);
    const int sBoff = ABYTES + gA * 1024 + ((rA << 4) ^ (gA << 5));

    // ---- fragment read offsets (constant per thread) ----
    int afoff[MI], bqoff[2];
    #pragma unroll
    for (int mi = 0; mi < MI; ++mi)
        afoff[mi] = kg * (BM * 16) + (((wr * (BM / 2) + mi * 16 + lr) << 4) ^ (kg << 5));
    #pragma unroll
    for (int ni = 0; ni < 2; ++ni)
        bqoff[ni] = ABYTES + kg * 1024 + (((wc * 32 + ni * 16 + lr) << 4) ^ (kg << 5));

    const bf16x8 z8 = {0,0,0,0,0,0,0,0};
    f32x4 acc[MI][2];
    #pragma unroll
    for (int mi = 0; mi < MI; ++mi)
        #pragma unroll
        for (int ni = 0; ni < 2; ++ni)
            acc[mi][ni] = (f32x4){0.f, 0.f, 0.f, 0.f};

    bf16x8 pA[ACH], pB;
    // ---- prologue: tile 0 -> regs -> LDS[0] ----
    #pragma unroll
    for (int it = 0; it < ACH; ++it)
        pA[it] = pAv[it] ? *(const bf16x8*)(aptr[it]) : z8;
    pB = pBv ? *(const bf16x8*)(bptr) : z8;
    #pragma unroll
    for (int it = 0; it < ACH; ++it) *(bf16x8*)(smem + sAoff[it]) = pA[it];
    *(bf16x8*)(smem + sBoff) = pB;
    __syncthreads();

    const int nt = K >> 5;
    for (int t = 0; t < nt; ++t) {
        const bool more = (t + 1 < nt);
        if (more) {
            const int kn = (t + 1) << 5;
            #pragma unroll
            for (int it = 0; it < ACH; ++it)
                pA[it] = pAv[it] ? *(const bf16x8*)(aptr[it] + kn) : z8;
            pB = pBv ? *(const bf16x8*)(bptr + kn) : z8;
        }
        const char* base = smem + (t & 1) * DBOF;
        bf16x8 af[MI], bq[2];
        #pragma unroll
        for (int mi = 0; mi < MI; ++mi) af[mi] = *(const bf16x8*)(base + afoff[mi]);
        #pragma unroll
        for (int ni = 0; ni < 2; ++ni) bq[ni] = *(const bf16x8*)(base + bqoff[ni]);
        #pragma unroll
        for (int mi = 0; mi < MI; ++mi)
            #pragma unroll
            for (int ni = 0; ni < 2; ++ni)
                acc[mi][ni] = __builtin_amdgcn_mfma_f32_16x16x32_bf16(
                    af[mi], bq[ni], acc[mi][ni], 0, 0, 0);
        if (more) {
            char* dst = smem + ((t + 1) & 1) * DBOF;
            #pragma unroll
            for (int it = 0; it < ACH; ++it) *(bf16x8*)(dst + sAoff[it]) = pA[it];
            *(bf16x8*)(dst + sBoff) = pB;
        }
        __syncthreads();
    }

    // ---- epilogue: D row=(lane>>4)*4+q, col=lane&15 ----
    #pragma unroll
    for (int mi = 0; mi < MI; ++mi) {
        #pragma unroll
        for (int ni = 0; ni < 2; ++ni) {
            #pragma unroll
            for (int q = 0; q < 4; ++q) {
                const int gm = m0 + wr * (BM / 2) + mi * 16 + kg * 4 + q;
                const int gn = n0 + wc * 32 + ni * 16 + lr;
                if (gm < M && gn < N) {
                    float v = acc[mi][ni][q] * alpha;
                    if (EPI >= 1) v += bias[gn];
                    const long ci = coff + (long)gm * ldc + gn;
                    if (EPI == 2) v = 0.5f * v * (1.0f + erff(v * 0.70710678118654752f));
                    if (EPI == 3) v += res[ci];
                    if (OUTBF) ((ushort*)Cv)[ci] = f2bf(v);
                    else       ((float*)Cv)[ci]  = v;
                }
            }
        }
    }
}

static inline void mgemm(hipStream_t st, int bm, int epi, bool outbf,
                         const ushort* A, int lda, const ushort* B, int ldb,
                         void* C, int ldc, const float* bias, const float* res,
                         int M, int N, int K, float alpha,
                         int batch, int nh,
                         long sAb, long sAh, long sBb, long sBh, long sCb, long sCh)
{
    dim3 g(CDIV(N, 64), CDIV(M, bm), batch);
    dim3 b(256);
#define MG(BMv, E, O) mgemm_k<BMv, E, O><<<g, b, 0, st>>>(A, lda, B, ldb, C, ldc, bias, res, M, N, K, alpha, nh, sAb, sAh, sBb, sBh, sCb, sCh)
    if (bm == 128) {
        if (epi == 0 && !outbf)      MG(128, 0, false);
        else if (epi == 0)           MG(128, 0, true);
        else if (epi == 1 && !outbf) MG(128, 1, false);
        else if (epi == 1)           MG(128, 1, true);
        else if (epi == 2)           MG(128, 2, true);
        else                         MG(128, 3, false);
    } else {
        if (epi == 0 && !outbf)      MG(64, 0, false);
        else if (epi == 0)           MG(64, 0, true);
        else if (epi == 1 && !outbf) MG(64, 1, false);
        else if (epi == 1)           MG(64, 1, true);
        else if (epi == 2)           MG(64, 2, true);
        else                         MG(64, 3, false);
    }
#undef MG
}

// ============== fp32 [K][N] -> bf16 [N][K] transpose (32x32 tiles) =========
__global__ __launch_bounds__(256) void wtrans_k(
    const float* __restrict__ in, ushort* __restrict__ out, int K, int N)
{
    __shared__ float t[32][33];
    const int k0 = blockIdx.y << 5, n0 = blockIdx.x << 5;
    const int tx = threadIdx.x, ty = threadIdx.y;
    #pragma unroll
    for (int j = 0; j < 32; j += 8)
        t[ty + j][tx] = in[(long)(k0 + ty + j) * N + n0 + tx];
    __syncthreads();
    #pragma unroll
    for (int j = 0; j < 32; j += 8)
        out[(long)(n0 + ty + j) * K + k0 + tx] = f2bf(t[tx][ty + j]);
}

// ===================== fp32 -> bf16 elementwise ============================
__global__ void cvt_k(const float* __restrict__ in, ushort* __restrict__ out, int n)
{
    const int i = blockIdx.x * 256 + threadIdx.x;
    if (i < n) out[i] = f2bf(in[i]);
}

// ====== LN over 768 (+optional window partition), bf16 output =============
__global__ __launch_bounds__(256) void ln_part_k(
    const float* __restrict__ x, ushort* __restrict__ y,
    const float* __restrict__ w, const float* __restrict__ b, int window)
{
    __shared__ float s1[256], s2[256];
    const int t = blockIdx.x, tid = threadIdx.x;
    int g = t; bool valid = true;
    if (window) {
        const int wi = t / 196, loc = t - wi * 196;
        const int wy = wi / 3, wx = wi - wy * 3;
        const int ly = loc / 14, lx = loc - ly * 14;
        const int gy = wy * 14 + ly, gx = wx * 14 + lx;
        valid = (gy < 32) && (gx < 32);
        g = gy * 32 + gx;
    }
    float xs[3] = {0.f, 0.f, 0.f};
    if (valid) {
        const float* xr = x + (long)g * 768;
        xs[0] = xr[tid]; xs[1] = xr[tid + 256]; xs[2] = xr[tid + 512];
    }
    s1[tid] = xs[0] + xs[1] + xs[2];
    s2[tid] = xs[0] * xs[0] + xs[1] * xs[1] + xs[2] * xs[2];
    __syncthreads();
    for (int off = 128; off > 0; off >>= 1) {
        if (tid < off) { s1[tid] += s1[tid + off]; s2[tid] += s2[tid + off]; }
        __syncthreads();
    }
    const float mean = s1[0] * (1.f / 768.f);
    const float var  = s2[0] * (1.f / 768.f) - mean * mean;
    const float rs   = rsqrtf(var + 1e-6f);
    ushort* yr = y + (long)t * 768;
    if (valid) {
        #pragma unroll
        for (int j = 0; j < 3; ++j) {
            const int c = tid + j * 256;
            yr[c] = f2bf((xs[j] - mean) * rs * w[c] + b[c]);
        }
    } else {
        #pragma unroll
        for (int j = 0; j < 3; ++j) yr[tid + j * 256] = 0;
    }
}

// ============ residual scatter-add (window unpartition crop) ===============
__global__ void scatter_add_k(float* __restrict__ h, const float* __restrict__ src, int window)
{
    const int idx = blockIdx.x * 256 + threadIdx.x;
    if (idx >= 1024 * 768) return;
    const int g = idx / 768, c = idx - g * 768;
    int t = g;
    if (window) {
        const int gy = g >> 5, gx = g & 31;
        const int wy = gy / 14, ly = gy - wy * 14;
        const int wx = gx / 14, lx = gx - wx * 14;
        t = (wy * 3 + wx) * 196 + ly * 14 + lx;
    }
    h[idx] += src[(long)t * 768 + c];
}

// ================== decomposed rel-pos dots (bf16 q) =======================
__global__ __launch_bounds__(64) void qrel_k(
    const ushort* __restrict__ qkv, const float* __restrict__ Rh, const float* __restrict__ Rw,
    float* __restrict__ relh, float* __restrict__ relw, int S, int H, int nh)
{
    const int row = blockIdx.x;               // z*S + t
    const int z = row / S, t = row - z * S;
    const int b = z / nh, hh = z - b * nh;
    const int r = threadIdx.x;
    const int W = H;
    const int qh = t / W, qw = t - qh * W;
    const ushort* q = qkv + ((long)(b * S + t)) * 2304 + hh * 64;
    if (r < H) {
        const float* R = Rh + (long)(qh - r + H - 1) * 64;
        float s = 0.f;
        for (int c = 0; c < 64; ++c) s += bf2f(q[c]) * R[c];
        relh[(long)row * H + r] = s;
    } else if (r < H + W) {
        const int r2 = r - H;
        const float* R = Rw + (long)(qw - r2 + W - 1) * 64;
        float s = 0.f;
        for (int c = 0; c < 64; ++c) s += bf2f(q[c]) * R[c];
        relw[(long)row * W + r2] = s;
    }
}

// ===== softmax (fp32 logits + rel) -> bf16 probs, zero-padded to Spad ======
__global__ __launch_bounds__(256) void softmax_rel_k(
    const float* __restrict__ attn, ushort* __restrict__ probs,
    const float* __restrict__ relh, const float* __restrict__ relw,
    int S, int W, int Spad)
{
    __shared__ float red[256];
    const long row = blockIdx.x;
    const int H = S / W;
    const float* a = attn + row * S;
    const int zz = (int)(row / S), t = (int)(row - (long)zz * S);
    ushort* p = probs + (long)zz * S * Spad + (long)t * Spad;
    const float* rh = relh + row * H;
    const float* rw = relw + row * W;
    const int tid = threadIdx.x;

    float vv[4];
    float mx = -1e30f;
    #pragma unroll
    for (int i = 0; i < 4; ++i) {
        const int j = tid + (i << 8);
        float v = -1e30f;
        if (j < S) {
            const int kh = j / W, kw = j - kh * W;
            v = a[j] + rh[kh] + rw[kw];
        }
        vv[i] = v;
        mx = fmaxf(mx, v);
    }
    red[tid] = mx; __syncthreads();
    for (int off = 128; off > 0; off >>= 1) {
        if (tid < off) red[tid] = fmaxf(red[tid], red[tid + off]);
        __syncthreads();
    }
    mx = red[0]; __syncthreads();
    float sum = 0.f;
    #pragma unroll
    for (int i = 0; i < 4; ++i) {
        const int j = tid + (i << 8);
        if (j < S) { const float e = __expf(vv[i] - mx); vv[i] = e; sum += e; }
    }
    red[tid] = sum; __syncthreads();
    for (int off = 128; off > 0; off >>= 1) {
        if (tid < off) red[tid] += red[tid + off];
        __syncthreads();
    }
    const float inv = 1.0f / red[0];
    #pragma unroll
    for (int i = 0; i < 4; ++i) {
        const int j = tid + (i << 8);
        if (j < S) p[j] = f2bf(vv[i] * inv);
    }
    for (int j = S + tid; j < Spad; j += 256) p[j] = 0;
}

// ===== v transpose: qkv v-part -> vT[z][64][Spad] bf16 (pad zeros) =========
__global__ void vT_k(const ushort* __restrict__ qkv, ushort* __restrict__ vT,
                     int S, int Spad, int total)
{
    const int idx = blockIdx.x * 256 + threadIdx.x;
    if (idx >= total) return;
    const int z = idx / (64 * Spad);
    const int rem = idx - z * 64 * Spad;
    const int c = rem / Spad, t = rem - c * Spad;
    const int bb = z / 12, hh = z - bb * 12;
    ushort v = 0;
    if (t < S) v = qkv[((long)(bb * S + t)) * 2304 + 1536 + hh * 64 + c];
    vT[idx] = v;
}

// ============================ misc =========================================
__global__ void im2col_patch_k(const float* __restrict__ x, ushort* __restrict__ xc)
{
    const int idx = blockIdx.x * 256 + threadIdx.x;
    if (idx >= 1024 * 768) return;
    const int t = idx / 768, k = idx - t * 768;
    const int ph = t >> 5, pw = t & 31;
    const int c = k >> 8, rem = k & 255;
    const int kh = rem >> 4, kw = rem & 15;
    xc[idx] = f2bf(x[((long)c * 512 + (ph * 16 + kh)) * 512 + (pw * 16 + kw)]);
}

__global__ void add_pos_k(float* __restrict__ h, const float* __restrict__ pos)
{
    const int idx = blockIdx.x * 256 + threadIdx.x;
    if (idx < 1024 * 768) h[idx] += pos[idx];
}

__global__ void im2col_neck_k(const float* __restrict__ in, ushort* __restrict__ xc)
{
    const int idx = blockIdx.x * 256 + threadIdx.x;
    if (idx >= 1024 * 2304) return;
    const int p = idx / 2304, k = idx - p * 2304;
    const int ci = k / 9, r = k - ci * 9;
    const int kh = r / 3, kw = r - kh * 3;
    const int gy = (p >> 5) + kh - 1, gx = (p & 31) + kw - 1;
    float v = 0.f;
    if (gy >= 0 && gy < 32 && gx >= 0 && gx < 32)
        v = in[((long)(gy * 32 + gx)) * 256 + ci];
    xc[idx] = f2bf(v);
}

__global__ __launch_bounds__(256) void ln2d_k(
    const float* __restrict__ x, float* __restrict__ y,
    const float* __restrict__ w, const float* __restrict__ b, int chw_out)
{
    __shared__ float s1[256], s2[256];
    const int p = blockIdx.x, c = threadIdx.x;
    const float v = x[(long)p * 256 + c];
    s1[c] = v; s2[c] = v * v;
    __syncthreads();
    for (int off = 128; off > 0; off >>= 1) {
        if (c < off) { s1[c] += s1[c + off]; s2[c] += s2[c + off]; }
        __syncthreads();
    }
    const float mean = s1[0] * (1.f / 256.f);
    const float var  = s2[0] * (1.f / 256.f) - mean * mean;
    const float out  = (v - mean) * rsqrtf(var + 1e-6f) * w[c] + b[c];
    if (chw_out) y[(long)c * 1024 + p] = out;
    else         y[(long)p * 256 + c] = out;
}

// =============================== driver ====================================
extern "C" void kernel_launch(void* const* d_in, const int* in_sizes, int n_in,
                              void* d_out, int out_size, void* d_ws, size_t ws_size,
                              hipStream_t stream)
{
    const float* x       = (const float*)d_in[0];
    const float* patch_w = (const float*)d_in[1];
    const float* patch_b = (const float*)d_in[2];
    const float* pos     = (const float*)d_in[3];
    const float* ln1_w   = (const float*)d_in[4];
    const float* ln1_b   = (const float*)d_in[5];
    const float* qkv_w   = (const float*)d_in[6];
    const float* qkv_b   = (const float*)d_in[7];
    const float* proj_w  = (const float*)d_in[8];
    const float* proj_b  = (const float*)d_in[9];
    const float* ln2_w   = (const float*)d_in[10];
    const float* ln2_b   = (const float*)d_in[11];
    const float* mlp1_w  = (const float*)d_in[12];
    const float* mlp1_b  = (const float*)d_in[13];
    const float* mlp2_w  = (const float*)d_in[14];
    const float* mlp2_b  = (const float*)d_in[15];
    const float* rhw     = (const float*)d_in[16];
    const float* rww     = (const float*)d_in[17];
    const float* rhg     = (const float*)d_in[18];
    const float* rwg     = (const float*)d_in[19];
    const float* neck_w1 = (const float*)d_in[20];
    const float* nln1_w  = (const float*)d_in[21];
    const float* nln1_b  = (const float*)d_in[22];
    const float* neck_w2 = (const float*)d_in[23];
    const float* nln2_w  = (const float*)d_in[24];
    const float* nln2_b  = (const float*)d_in[25];
    (void)in_sizes; (void)n_in; (void)out_size; (void)ws_size;

    char* cur = (char*)d_ws;
    auto alloc = [&](size_t bytes) -> char* {
        char* p = cur; cur += (bytes + 255) & ~(size_t)255; return p;
    };
    float*  h      = (float*) alloc(1024l * 768 * 4);
    ushort* ybf    = (ushort*)alloc(1764l * 768 * 2);
    ushort* qkvbf  = (ushort*)alloc(1764l * 2304 * 2);
    float*  attn   = (float*) alloc(12l * 1024 * 1024 * 4);
    ushort* probs  = (ushort*)alloc(12l * 1024 * 1024 * 2);
    ushort* obf    = (ushort*)alloc(1764l * 768 * 2);
    float*  tb     = (float*) alloc(1024l * 3072 * 4);
    float*  relh   = (float*) alloc(12l * 1024 * 32 * 4);
    float*  relw   = (float*) alloc(12l * 1024 * 32 * 4);
    ushort* vT     = (ushort*)alloc(108l * 64 * 224 * 2);
    ushort* qkvT   = (ushort*)alloc(2304l * 768 * 2);
    ushort* projT  = (ushort*)alloc(768l * 768 * 2);
    ushort* m1T    = (ushort*)alloc(3072l * 768 * 2);
    ushort* m2T    = (ushort*)alloc(768l * 3072 * 2);
    ushort* patchbf= (ushort*)alloc(768l * 768 * 2);
    ushort* xc     = (ushort*)alloc(1024l * 768 * 2);
    ushort* xcn    = (ushort*)alloc(1024l * 2304 * 2);
    ushort* hbf    = (ushort*)alloc(1024l * 768 * 2);
    ushort* nw1bf  = (ushort*)alloc(256l * 768 * 2);
    ushort* nw2bf  = (ushort*)alloc(256l * 2304 * 2);
    float*  nk1    = (float*) alloc(1024l * 256 * 4);
    float*  nk2    = (float*) alloc(1024l * 256 * 4);

    // ---- one-time weight converts (already [N][K] layouts) ----
    cvt_k<<<CDIV(768 * 768, 256), 256, 0, stream>>>(patch_w, patchbf, 768 * 768);
    cvt_k<<<CDIV(256 * 768, 256), 256, 0, stream>>>(neck_w1, nw1bf, 256 * 768);
    cvt_k<<<CDIV(256 * 2304, 256), 256, 0, stream>>>(neck_w2, nw2bf, 256 * 2304);

    // ---- patch embed ----
    im2col_patch_k<<<CDIV(786432, 256), 256, 0, stream>>>(x, xc);
    mgemm(stream, 64, 1, false, xc, 768, patchbf, 768, h, 768, patch_b, nullptr,
          1024, 768, 768, 1.f, 1, 1, 0, 0, 0, 0, 0, 0);
    add_pos_k<<<CDIV(786432, 256), 256, 0, stream>>>(h, pos);

    int wi = 0, gi = 0;
    for (int i = 0; i < 12; ++i) {
        const bool glb = (i == 2) || (i == 5) || (i == 8) || (i == 11);
        const int S  = glb ? 1024 : 196;
        const int Spad = glb ? 1024 : 224;
        const int nB = glb ? 1 : 9;
        const int ntok = nB * S;
        const int HH = glb ? 32 : 14;
        const int Z  = nB * 12;

        // per-layer weight transposes [K][N] -> bf16 [N][K]
        wtrans_k<<<dim3(2304/32, 768/32),  dim3(32,8), 0, stream>>>(qkv_w  + (long)i*768*2304, qkvT, 768, 2304);
        wtrans_k<<<dim3(768/32,  768/32),  dim3(32,8), 0, stream>>>(proj_w + (long)i*768*768,  projT, 768, 768);
        wtrans_k<<<dim3(3072/32, 768/32),  dim3(32,8), 0, stream>>>(mlp1_w + (long)i*768*3072, m1T,  768, 3072);
        wtrans_k<<<dim3(768/32,  3072/32), dim3(32,8), 0, stream>>>(mlp2_w + (long)i*3072*768, m2T, 3072, 768);

        // LN1 (+window partition, zero pad) -> bf16
        ln_part_k<<<ntok, 256, 0, stream>>>(h, ybf, ln1_w + i*768, ln1_b + i*768, glb ? 0 : 1);
        // QKV -> bf16
        mgemm(stream, 128, 1, true, ybf, 768, qkvT, 768, qkvbf, 2304, qkv_b + i*2304, nullptr,
              ntok, 2304, 768, 1.f, 1, 1, 0, 0, 0, 0, 0, 0);
        // QK^T (alpha = 1/8) -> fp32 logits
        mgemm(stream, glb ? 128 : 64, 0, false, qkvbf, 2304, qkvbf + 768, 2304, attn, S, nullptr, nullptr,
              S, S, 64, 0.125f, Z, 12,
              (long)S * 2304, 64, (long)S * 2304, 64, (long)12 * S * S, (long)S * S);
        // rel-pos dots (unscaled q)
        const float* Rh = glb ? (rhg + (long)gi * 63 * 64) : (rhw + (long)wi * 27 * 64);
        const float* Rw = glb ? (rwg + (long)gi * 63 * 64) : (rww + (long)wi * 27 * 64);
        qrel_k<<<Z * S, 64, 0, stream>>>(qkvbf, Rh, Rw, relh, relw, S, HH, 12);
        // v transpose -> vT[z][64][Spad]
        {
            const int tot = Z * 64 * Spad;
            vT_k<<<CDIV(tot, 256), 256, 0, stream>>>(qkvbf, vT, S, Spad, tot);
        }
        // softmax + rel -> bf16 probs (padded)
        softmax_rel_k<<<Z * S, 256, 0, stream>>>(attn, probs, relh, relw, S, HH, Spad);
        // P @ V -> obf (bf16, heads scattered token-major)
        mgemm(stream, 64, 0, true, probs, Spad, vT, Spad, obf, 768, nullptr, nullptr,
              S, 64, Spad, 1.f, Z, 12,
              (long)12 * S * Spad, (long)S * Spad, (long)12 * 64 * Spad, (long)64 * Spad,
              (long)S * 768, 64);
        // proj + bias
        mgemm(stream, 64, 1, false, obf, 768, projT, 768, tb, 768, proj_b + i*768, nullptr,
              ntok, 768, 768, 1.f, 1, 1, 0, 0, 0, 0, 0, 0);
        // residual (window unpartition crop)
        scatter_add_k<<<CDIV(786432, 256), 256, 0, stream>>>(h, tb, glb ? 0 : 1);
        // MLP
        ln_part_k<<<1024, 256, 0, stream>>>(h, ybf, ln2_w + i*768, ln2_b + i*768, 0);
        mgemm(stream, 128, 2, true, ybf, 768, m1T, 768, tb, 3072, mlp1_b + i*3072, nullptr,
              1024, 3072, 768, 1.f, 1, 1, 0, 0, 0, 0, 0, 0);
        mgemm(stream, 64, 3, false, (ushort*)tb, 3072, m2T, 3072, h, 768, mlp2_b + i*768, h,
              1024, 768, 3072, 1.f, 1, 1, 0, 0, 0, 0, 0, 0);

        if (glb) gi++; else wi++;
    }

    // ---- neck ----
    cvt_k<<<CDIV(786432, 256), 256, 0, stream>>>(h, hbf, 786432);
    mgemm(stream, 64, 0, false, hbf, 768, nw1bf, 768, nk1, 256, nullptr, nullptr,
          1024, 256, 768, 1.f, 1, 1, 0, 0, 0, 0, 0, 0);
    ln2d_k<<<1024, 256, 0, stream>>>(nk1, nk2, nln1_w, nln1_b, 0);
    im2col_neck_k<<<CDIV(1024 * 2304, 256), 256, 0, stream>>>(nk2, xcn);
    mgemm(stream, 64, 0, false, xcn, 2304, nw2bf, 2304, nk1, 256, nullptr, nullptr,
          1024, 256, 2304, 1.f, 1, 1, 0, 0, 0, 0, 0, 0);
    ln2d_k<<<1024, 256, 0, stream>>>(nk1, (float*)d_out, nln2_w, nln2_b, 1);
}

// Round 7
// 2852.233 us; speedup vs baseline: 2.7760x; 1.0356x over previous
//
#include <hip/hip_runtime.h>
#include <hip/hip_bf16.h>
#include <math.h>

#define CDIV(a,b) (((a)+(b)-1)/(b))

typedef short bf16x8 __attribute__((ext_vector_type(8)));
typedef float f32x4 __attribute__((ext_vector_type(4)));

__device__ __forceinline__ ushort f2bf(float f){
    __hip_bfloat16 h = __float2bfloat16(f);
    return *reinterpret_cast<ushort*>(&h);
}
__device__ __forceinline__ float bf2f(ushort u){
    __hip_bfloat16 h;
    *reinterpret_cast<ushort*>(&h) = u;
    return __bfloat162float(h);
}

// ====================== bf16 MFMA GEMM (pipelined, dbuf) ===================
// C[M,N] = alpha * A[M,K](bf16 rm) @ B[N,K](bf16 rm)^T
// EPI: 0 none | 1 +bias | 2 +bias,gelu | 3 +bias,+res(fp32)
template<int BM, int EPI, bool OUTBF>
__global__ __launch_bounds__(256) void mgemm_k(
    const ushort* __restrict__ A, int lda,
    const ushort* __restrict__ B, int ldb,
    void* __restrict__ Cv, int ldc,
    const float* __restrict__ bias, const float* __restrict__ res,
    int M, int N, int K, float alpha, int nh,
    long sAb, long sAh, long sBb, long sBh, long sCb, long sCh)
{
    constexpr int MI = BM / 32;
    constexpr int ACH = BM / 64;
    constexpr int ABYTES = BM * 64;
    constexpr int DBOF = ABYTES + 4096;

    const int z = blockIdx.z;
    const int bb = z / nh, hh = z - bb * nh;
    A += bb * sAb + hh * sAh;
    B += bb * sBb + hh * sBh;
    const long coff = bb * sCb + hh * sCh;

    __shared__ __align__(16) char smem[2 * DBOF];

    const int tid = threadIdx.x;
    const int m0 = blockIdx.y * BM;
    const int n0 = blockIdx.x * 64;
    const int lane = tid & 63;
    const int w = tid >> 6;
    const int wr = w >> 1, wc = w & 1;
    const int kg = lane >> 4, lr = lane & 15;

    const int rA = tid >> 2, gA = tid & 3;
    const ushort* aptr[ACH]; bool pAv[ACH]; int sAoff[ACH];
    #pragma unroll
    for (int it = 0; it < ACH; ++it) {
        const int gm = m0 + rA + it * 64;
        pAv[it] = gm < M;
        const int cm = pAv[it] ? gm : (M > 0 ? M - 1 : 0);
        aptr[it] = A + (long)cm * lda + (gA << 3);
        sAoff[it] = gA * (BM * 16) + ((rA << 4) ^ (gA << 5)) + it * 1024;
    }
    const int gn_s = n0 + rA;
    const bool pBv = gn_s < N;
    const ushort* bptr = B + (long)(pBv ? gn_s : (N - 1)) * ldb + (gA << 3);
    const int sBoff = ABYTES + gA * 1024 + ((rA << 4) ^ (gA << 5));

    int afoff[MI], bqoff[2];
    #pragma unroll
    for (int mi = 0; mi < MI; ++mi)
        afoff[mi] = kg * (BM * 16) + (((wr * (BM / 2) + mi * 16 + lr) << 4) ^ (kg << 5));
    #pragma unroll
    for (int ni = 0; ni < 2; ++ni)
        bqoff[ni] = ABYTES + kg * 1024 + (((wc * 32 + ni * 16 + lr) << 4) ^ (kg << 5));

    const bf16x8 z8 = {0,0,0,0,0,0,0,0};
    f32x4 acc[MI][2];
    #pragma unroll
    for (int mi = 0; mi < MI; ++mi)
        #pragma unroll
        for (int ni = 0; ni < 2; ++ni)
            acc[mi][ni] = (f32x4){0.f, 0.f, 0.f, 0.f};

    bf16x8 pA[ACH], pB;
    #pragma unroll
    for (int it = 0; it < ACH; ++it)
        pA[it] = pAv[it] ? *(const bf16x8*)(aptr[it]) : z8;
    pB = pBv ? *(const bf16x8*)(bptr) : z8;
    #pragma unroll
    for (int it = 0; it < ACH; ++it) *(bf16x8*)(smem + sAoff[it]) = pA[it];
    *(bf16x8*)(smem + sBoff) = pB;
    __syncthreads();

    const int nt = K >> 5;
    for (int t = 0; t < nt; ++t) {
        const bool more = (t + 1 < nt);
        if (more) {
            const int kn = (t + 1) << 5;
            #pragma unroll
            for (int it = 0; it < ACH; ++it)
                pA[it] = pAv[it] ? *(const bf16x8*)(aptr[it] + kn) : z8;
            pB = pBv ? *(const bf16x8*)(bptr + kn) : z8;
        }
        const char* base = smem + (t & 1) * DBOF;
        bf16x8 af[MI], bq[2];
        #pragma unroll
        for (int mi = 0; mi < MI; ++mi) af[mi] = *(const bf16x8*)(base + afoff[mi]);
        #pragma unroll
        for (int ni = 0; ni < 2; ++ni) bq[ni] = *(const bf16x8*)(base + bqoff[ni]);
        #pragma unroll
        for (int mi = 0; mi < MI; ++mi)
            #pragma unroll
            for (int ni = 0; ni < 2; ++ni)
                acc[mi][ni] = __builtin_amdgcn_mfma_f32_16x16x32_bf16(
                    af[mi], bq[ni], acc[mi][ni], 0, 0, 0);
        if (more) {
            char* dst = smem + ((t + 1) & 1) * DBOF;
            #pragma unroll
            for (int it = 0; it < ACH; ++it) *(bf16x8*)(dst + sAoff[it]) = pA[it];
            *(bf16x8*)(dst + sBoff) = pB;
        }
        __syncthreads();
    }

    #pragma unroll
    for (int mi = 0; mi < MI; ++mi) {
        #pragma unroll
        for (int ni = 0; ni < 2; ++ni) {
            #pragma unroll
            for (int q = 0; q < 4; ++q) {
                const int gm = m0 + wr * (BM / 2) + mi * 16 + kg * 4 + q;
                const int gn = n0 + wc * 32 + ni * 16 + lr;
                if (gm < M && gn < N) {
                    float v = acc[mi][ni][q] * alpha;
                    if (EPI >= 1) v += bias[gn];
                    const long ci = coff + (long)gm * ldc + gn;
                    if (EPI == 2) v = 0.5f * v * (1.0f + erff(v * 0.70710678118654752f));
                    if (EPI == 3) v += res[ci];
                    if (OUTBF) ((ushort*)Cv)[ci] = f2bf(v);
                    else       ((float*)Cv)[ci]  = v;
                }
            }
        }
    }
}

static inline void mgemm(hipStream_t st, int bm, int epi, bool outbf,
                         const ushort* A, int lda, const ushort* B, int ldb,
                         void* C, int ldc, const float* bias, const float* res,
                         int M, int N, int K, float alpha,
                         int batch, int nh,
                         long sAb, long sAh, long sBb, long sBh, long sCb, long sCh)
{
    dim3 g(CDIV(N, 64), CDIV(M, bm), batch);
    dim3 b(256);
#define MG(BMv, E, O) mgemm_k<BMv, E, O><<<g, b, 0, st>>>(A, lda, B, ldb, C, ldc, bias, res, M, N, K, alpha, nh, sAb, sAh, sBb, sBh, sCb, sCh)
    if (bm == 128) {
        if (epi == 0 && !outbf)      MG(128, 0, false);
        else if (epi == 0)           MG(128, 0, true);
        else if (epi == 1 && !outbf) MG(128, 1, false);
        else if (epi == 1)           MG(128, 1, true);
        else if (epi == 2)           MG(128, 2, true);
        else                         MG(128, 3, false);
    } else {
        if (epi == 0 && !outbf)      MG(64, 0, false);
        else if (epi == 0)           MG(64, 0, true);
        else if (epi == 1 && !outbf) MG(64, 1, false);
        else if (epi == 1)           MG(64, 1, true);
        else if (epi == 2)           MG(64, 2, true);
        else                         MG(64, 3, false);
    }
#undef MG
}

// ================= fused flash attention (per z, per 32-row Q-tile) ========
// qkv: [bb*S+t][2304] bf16 (q at +0, k at +768)
// vT:  [z][64][Spad] bf16 (zero-padded)   relh/relw: [(z*S+t)*HH] fp32
// obf: [bb*S+t][768] bf16, head block at hh*64.
__global__ __launch_bounds__(128) void fattn_k(
    const ushort* __restrict__ qkv, const ushort* __restrict__ vT,
    const float* __restrict__ relh, const float* __restrict__ relw,
    ushort* __restrict__ obf, int S, int Spad, int HH, int nh)
{
    const int z = blockIdx.y;
    const int bb = z / nh, hh = z - bb * nh;
    const int qt0 = blockIdx.x * 32;
    const int tid = threadIdx.x;
    const int lane = tid & 63;
    const int w = tid >> 6;                 // wave 0/1 -> q rows [qt0+w*16, +16)
    const int lr = lane & 15, kg = lane >> 4;
    const bf16x8 z8 = {0,0,0,0,0,0,0,0};

    __shared__ __align__(16) char smem[20480];   // sK 8K | sVT 8K | sP 2x2K
    char* sK  = smem;
    char* sVT = smem + 8192;
    char* sP  = smem + 16384 + w * 2048;

    // Q fragments (A-operand): row = qt0 + w*16 + lr, k = st*32 + kg*8
    const int qrow = qt0 + w * 16 + lr;
    const bool qv = qrow < S;
    const ushort* qp = qkv + ((long)(bb * S + (qv ? qrow : 0))) * 2304 + hh * 64 + (kg << 3);
    bf16x8 qf[2];
    qf[0] = qv ? *(const bf16x8*)(qp)      : z8;
    qf[1] = qv ? *(const bf16x8*)(qp + 32) : z8;

    f32x4 m = {-1e30f, -1e30f, -1e30f, -1e30f};
    f32x4 l = {0.f, 0.f, 0.f, 0.f};
    f32x4 o[4];
    #pragma unroll
    for (int i = 0; i < 4; ++i) o[i] = (f32x4){0.f, 0.f, 0.f, 0.f};

    // stats rows for this lane: t(qi) = qt0 + w*16 + kg*4 + qi
    const int trow0 = qt0 + w * 16 + kg * 4;
    const long relbase = ((long)z * S + trow0) * HH;   // + qi*HH

    for (int c0 = 0; c0 < S; c0 += 64) {
        __syncthreads();
        // ---- stage K chunk: keys c0+n (n 0..63) x 64 k ----
        #pragma unroll
        for (int it = 0; it < 4; ++it) {
            const int cc = tid + it * 128;
            const int n = cc >> 3, ch = cc & 7;
            const int kb = ch >> 2, g = ch & 3;
            const int tok = c0 + n;
            bf16x8 v = z8;
            if (tok < S)
                v = *(const bf16x8*)(qkv + ((long)(bb * S + tok)) * 2304 + 768 + hh * 64 + ch * 8);
            *(bf16x8*)(sK + kb * 4096 + g * 1024 + ((n << 4) ^ (g << 5))) = v;
        }
        // ---- stage VT chunk: rows d (0..63) x keys c0..c0+63 ----
        #pragma unroll
        for (int it = 0; it < 4; ++it) {
            const int cc = tid + it * 128;
            const int d = cc >> 3, ch = cc & 7;
            const int kb = ch >> 2, g = ch & 3;
            const int key = c0 + ch * 8;
            bf16x8 v = z8;
            if (key < Spad)
                v = *(const bf16x8*)(vT + ((long)(z * 64 + d)) * Spad + key);
            *(bf16x8*)(sVT + kb * 4096 + g * 1024 + ((d << 4) ^ (g << 5))) = v;
        }
        __syncthreads();

        // ---- S = q.k^T : 4 key tiles x 2 ksteps ----
        f32x4 s[4];
        #pragma unroll
        for (int ntl = 0; ntl < 4; ++ntl) s[ntl] = (f32x4){0.f, 0.f, 0.f, 0.f};
        #pragma unroll
        for (int stp = 0; stp < 2; ++stp) {
            #pragma unroll
            for (int ntl = 0; ntl < 4; ++ntl) {
                const bf16x8 kf = *(const bf16x8*)(sK + stp * 4096 + kg * 1024 +
                                   (((ntl * 16 + lr) << 4) ^ (kg << 5)));
                s[ntl] = __builtin_amdgcn_mfma_f32_16x16x32_bf16(qf[stp], kf, s[ntl], 0, 0, 0);
            }
        }
        // ---- logits: scale + rel, mask invalid ----
        #pragma unroll
        for (int ntl = 0; ntl < 4; ++ntl) {
            const int j = c0 + ntl * 16 + lr;
            #pragma unroll
            for (int qi = 0; qi < 4; ++qi) {
                const int t = trow0 + qi;
                float v;
                if (t < S && j < S) {
                    const int kh = j / HH, kw = j - kh * HH;
                    const long rb = relbase + (long)qi * HH;
                    v = s[ntl][qi] * 0.125f + relh[rb + kh] + relw[rb + kw];
                } else v = -1e30f;
                s[ntl][qi] = v;
            }
        }
        // ---- online softmax ----
        f32x4 mn, rsum, sc;
        #pragma unroll
        for (int qi = 0; qi < 4; ++qi) {
            float r = fmaxf(fmaxf(s[0][qi], s[1][qi]), fmaxf(s[2][qi], s[3][qi]));
            #pragma unroll
            for (int d = 1; d < 16; d <<= 1) r = fmaxf(r, __shfl_xor(r, d, 16));
            mn[qi] = fmaxf(m[qi], r);
        }
        #pragma unroll
        for (int qi = 0; qi < 4; ++qi) {
            float sum = 0.f;
            #pragma unroll
            for (int ntl = 0; ntl < 4; ++ntl) {
                const float e = __expf(s[ntl][qi] - mn[qi]);
                s[ntl][qi] = e;
                sum += e;
            }
            #pragma unroll
            for (int d = 1; d < 16; d <<= 1) sum += __shfl_xor(sum, d, 16);
            rsum[qi] = sum;
            sc[qi] = __expf(m[qi] - mn[qi]);
            l[qi] = l[qi] * sc[qi] + rsum[qi];
            m[qi] = mn[qi];
        }
        #pragma unroll
        for (int ntl = 0; ntl < 4; ++ntl) o[ntl] = o[ntl] * sc;

        // ---- P (D-layout) -> LDS (A-layout source), bf16 ----
        #pragma unroll
        for (int ntl = 0; ntl < 4; ++ntl) {
            #pragma unroll
            for (int qi = 0; qi < 4; ++qi) {
                const int r = kg * 4 + qi;
                *(ushort*)(sP + r * 128 + ((((ntl * 16 + lr) << 1)) ^ ((r >> 2) << 5))) =
                    f2bf(s[ntl][qi]);
            }
        }
        // ---- PV: o += P @ V^T-tiles (same-wave LDS dependency) ----
        #pragma unroll
        for (int stp = 0; stp < 2; ++stp) {
            const bf16x8 pa = *(const bf16x8*)(sP + lr * 128 +
                               (((stp * 64 + kg * 16)) ^ ((lr >> 2) << 5)));
            #pragma unroll
            for (int ntd = 0; ntd < 4; ++ntd) {
                const bf16x8 vb = *(const bf16x8*)(sVT + stp * 4096 + kg * 1024 +
                                   (((ntd * 16 + lr) << 4) ^ (kg << 5)));
                o[ntd] = __builtin_amdgcn_mfma_f32_16x16x32_bf16(pa, vb, o[ntd], 0, 0, 0);
            }
        }
    }

    // ---- output ----
    #pragma unroll
    for (int qi = 0; qi < 4; ++qi) {
        const int t = trow0 + qi;
        if (t < S) {
            const float inv = 1.0f / l[qi];
            ushort* op = obf + ((long)(bb * S + t)) * 768 + hh * 64 + lr;
            #pragma unroll
            for (int ntd = 0; ntd < 4; ++ntd)
                op[ntd * 16] = f2bf(o[ntd][qi] * inv);
        }
    }
}

// ====== batched fp32 [K][N] -> bf16 [N][K] transpose, layer = blockIdx.z ===
__global__ __launch_bounds__(256) void wtrans_all_k(
    const float* __restrict__ in, ushort* __restrict__ out, int K, int N)
{
    __shared__ float t[32][33];
    const long loff = (long)blockIdx.z * K * N;
    in += loff; out += loff;
    const int k0 = blockIdx.y << 5, n0 = blockIdx.x << 5;
    const int tx = threadIdx.x, ty = threadIdx.y;
    #pragma unroll
    for (int j = 0; j < 32; j += 8)
        t[ty + j][tx] = in[(long)(k0 + ty + j) * N + n0 + tx];
    __syncthreads();
    #pragma unroll
    for (int j = 0; j < 32; j += 8)
        out[(long)(n0 + ty + j) * K + k0 + tx] = f2bf(t[tx][ty + j]);
}

__global__ void cvt_k(const float* __restrict__ in, ushort* __restrict__ out, int n)
{
    const int i = blockIdx.x * 256 + threadIdx.x;
    if (i < n) out[i] = f2bf(in[i]);
}

// ====== LN over 768 (+optional window partition), bf16 output =============
__global__ __launch_bounds__(256) void ln_part_k(
    const float* __restrict__ x, ushort* __restrict__ y,
    const float* __restrict__ w, const float* __restrict__ b, int window)
{
    __shared__ float s1[256], s2[256];
    const int t = blockIdx.x, tid = threadIdx.x;
    int g = t; bool valid = true;
    if (window) {
        const int wi = t / 196, loc = t - wi * 196;
        const int wy = wi / 3, wx = wi - wy * 3;
        const int ly = loc / 14, lx = loc - ly * 14;
        const int gy = wy * 14 + ly, gx = wx * 14 + lx;
        valid = (gy < 32) && (gx < 32);
        g = gy * 32 + gx;
    }
    float xs[3] = {0.f, 0.f, 0.f};
    if (valid) {
        const float* xr = x + (long)g * 768;
        xs[0] = xr[tid]; xs[1] = xr[tid + 256]; xs[2] = xr[tid + 512];
    }
    s1[tid] = xs[0] + xs[1] + xs[2];
    s2[tid] = xs[0] * xs[0] + xs[1] * xs[1] + xs[2] * xs[2];
    __syncthreads();
    for (int off = 128; off > 0; off >>= 1) {
        if (tid < off) { s1[tid] += s1[tid + off]; s2[tid] += s2[tid + off]; }
        __syncthreads();
    }
    const float mean = s1[0] * (1.f / 768.f);
    const float var  = s2[0] * (1.f / 768.f) - mean * mean;
    const float rs   = rsqrtf(var + 1e-6f);
    ushort* yr = y + (long)t * 768;
    if (valid) {
        #pragma unroll
        for (int j = 0; j < 3; ++j) {
            const int c = tid + j * 256;
            yr[c] = f2bf((xs[j] - mean) * rs * w[c] + b[c]);
        }
    } else {
        #pragma unroll
        for (int j = 0; j < 3; ++j) yr[tid + j * 256] = 0;
    }
}

// ====== fused residual-add (window unpartition) + LN2 -> bf16 ==============
__global__ __launch_bounds__(256) void res_ln_k(
    float* __restrict__ h, const float* __restrict__ src, int window,
    const float* __restrict__ w, const float* __restrict__ b, ushort* __restrict__ y)
{
    __shared__ float s1[256], s2[256];
    const int g = blockIdx.x, tid = threadIdx.x;
    int t = g;
    if (window) {
        const int gy = g >> 5, gx = g & 31;
        const int wy = gy / 14, ly = gy - wy * 14;
        const int wx = gx / 14, lx = gx - wx * 14;
        t = (wy * 3 + wx) * 196 + ly * 14 + lx;
    }
    float xs[3];
    #pragma unroll
    for (int j = 0; j < 3; ++j) {
        const int c = tid + j * 256;
        xs[j] = h[(long)g * 768 + c] + src[(long)t * 768 + c];
        h[(long)g * 768 + c] = xs[j];
    }
    s1[tid] = xs[0] + xs[1] + xs[2];
    s2[tid] = xs[0] * xs[0] + xs[1] * xs[1] + xs[2] * xs[2];
    __syncthreads();
    for (int off = 128; off > 0; off >>= 1) {
        if (tid < off) { s1[tid] += s1[tid + off]; s2[tid] += s2[tid + off]; }
        __syncthreads();
    }
    const float mean = s1[0] * (1.f / 768.f);
    const float var  = s2[0] * (1.f / 768.f) - mean * mean;
    const float rs   = rsqrtf(var + 1e-6f);
    #pragma unroll
    for (int j = 0; j < 3; ++j) {
        const int c = tid + j * 256;
        y[(long)g * 768 + c] = f2bf((xs[j] - mean) * rs * w[c] + b[c]);
    }
}

// ================== decomposed rel-pos dots (bf16 q) =======================
__global__ __launch_bounds__(64) void qrel_k(
    const ushort* __restrict__ qkv, const float* __restrict__ Rh, const float* __restrict__ Rw,
    float* __restrict__ relh, float* __restrict__ relw, int S, int H, int nh)
{
    const int row = blockIdx.x;
    const int z = row / S, t = row - z * S;
    const int b = z / nh, hh = z - b * nh;
    const int r = threadIdx.x;
    const int W = H;
    const int qh = t / W, qw = t - qh * W;
    const ushort* q = qkv + ((long)(b * S + t)) * 2304 + hh * 64;
    if (r < H) {
        const float* R = Rh + (long)(qh - r + H - 1) * 64;
        float s = 0.f;
        for (int c = 0; c < 64; ++c) s += bf2f(q[c]) * R[c];
        relh[(long)row * H + r] = s;
    } else if (r < H + W) {
        const int r2 = r - H;
        const float* R = Rw + (long)(qw - r2 + W - 1) * 64;
        float s = 0.f;
        for (int c = 0; c < 64; ++c) s += bf2f(q[c]) * R[c];
        relw[(long)row * W + r2] = s;
    }
}

// ===== v transpose: qkv v-part -> vT[z][64][Spad] bf16 (pad zeros) =========
__global__ void vT_k(const ushort* __restrict__ qkv, ushort* __restrict__ vT,
                     int S, int Spad, int total)
{
    const int idx = blockIdx.x * 256 + threadIdx.x;
    if (idx >= total) return;
    const int z = idx / (64 * Spad);
    const int rem = idx - z * 64 * Spad;
    const int c = rem / Spad, t = rem - c * Spad;
    const int bb = z / 12, hh = z - bb * 12;
    ushort v = 0;
    if (t < S) v = qkv[((long)(bb * S + t)) * 2304 + 1536 + hh * 64 + c];
    vT[idx] = v;
}

// ============================ misc =========================================
__global__ void im2col_patch_k(const float* __restrict__ x, ushort* __restrict__ xc)
{
    const int idx = blockIdx.x * 256 + threadIdx.x;
    if (idx >= 1024 * 768) return;
    const int t = idx / 768, k = idx - t * 768;
    const int ph = t >> 5, pw = t & 31;
    const int c = k >> 8, rem = k & 255;
    const int kh = rem >> 4, kw = rem & 15;
    xc[idx] = f2bf(x[((long)c * 512 + (ph * 16 + kh)) * 512 + (pw * 16 + kw)]);
}

__global__ void add_pos_k(float* __restrict__ h, const float* __restrict__ pos)
{
    const int idx = blockIdx.x * 256 + threadIdx.x;
    if (idx < 1024 * 768) h[idx] += pos[idx];
}

__global__ void im2col_neck_k(const float* __restrict__ in, ushort* __restrict__ xc)
{
    const int idx = blockIdx.x * 256 + threadIdx.x;
    if (idx >= 1024 * 2304) return;
    const int p = idx / 2304, k = idx - p * 2304;
    const int ci = k / 9, r = k - ci * 9;
    const int kh = r / 3, kw = r - kh * 3;
    const int gy = (p >> 5) + kh - 1, gx = (p & 31) + kw - 1;
    float v = 0.f;
    if (gy >= 0 && gy < 32 && gx >= 0 && gx < 32)
        v = in[((long)(gy * 32 + gx)) * 256 + ci];
    xc[idx] = f2bf(v);
}

__global__ __launch_bounds__(256) void ln2d_k(
    const float* __restrict__ x, float* __restrict__ y,
    const float* __restrict__ w, const float* __restrict__ b, int chw_out)
{
    __shared__ float s1[256], s2[256];
    const int p = blockIdx.x, c = threadIdx.x;
    const float v = x[(long)p * 256 + c];
    s1[c] = v; s2[c] = v * v;
    __syncthreads();
    for (int off = 128; off > 0; off >>= 1) {
        if (c < off) { s1[c] += s1[c + off]; s2[c] += s2[c + off]; }
        __syncthreads();
    }
    const float mean = s1[0] * (1.f / 256.f);
    const float var  = s2[0] * (1.f / 256.f) - mean * mean;
    const float out  = (v - mean) * rsqrtf(var + 1e-6f) * w[c] + b[c];
    if (chw_out) y[(long)c * 1024 + p] = out;
    else         y[(long)p * 256 + c] = out;
}

// =============================== driver ====================================
extern "C" void kernel_launch(void* const* d_in, const int* in_sizes, int n_in,
                              void* d_out, int out_size, void* d_ws, size_t ws_size,
                              hipStream_t stream)
{
    const float* x       = (const float*)d_in[0];
    const float* patch_w = (const float*)d_in[1];
    const float* patch_b = (const float*)d_in[2];
    const float* pos     = (const float*)d_in[3];
    const float* ln1_w   = (const float*)d_in[4];
    const float* ln1_b   = (const float*)d_in[5];
    const float* qkv_w   = (const float*)d_in[6];
    const float* qkv_b   = (const float*)d_in[7];
    const float* proj_w  = (const float*)d_in[8];
    const float* proj_b  = (const float*)d_in[9];
    const float* ln2_w   = (const float*)d_in[10];
    const float* ln2_b   = (const float*)d_in[11];
    const float* mlp1_w  = (const float*)d_in[12];
    const float* mlp1_b  = (const float*)d_in[13];
    const float* mlp2_w  = (const float*)d_in[14];
    const float* mlp2_b  = (const float*)d_in[15];
    const float* rhw     = (const float*)d_in[16];
    const float* rww     = (const float*)d_in[17];
    const float* rhg     = (const float*)d_in[18];
    const float* rwg     = (const float*)d_in[19];
    const float* neck_w1 = (const float*)d_in[20];
    const float* nln1_w  = (const float*)d_in[21];
    const float* nln1_b  = (const float*)d_in[22];
    const float* neck_w2 = (const float*)d_in[23];
    const float* nln2_w  = (const float*)d_in[24];
    const float* nln2_b  = (const float*)d_in[25];
    (void)in_sizes; (void)n_in; (void)out_size; (void)ws_size;

    char* cur = (char*)d_ws;
    auto alloc = [&](size_t bytes) -> char* {
        char* p = cur; cur += (bytes + 255) & ~(size_t)255; return p;
    };
    float*  h      = (float*) alloc(1024l * 768 * 4);
    ushort* ybf    = (ushort*)alloc(1764l * 768 * 2);
    ushort* qkvbf  = (ushort*)alloc(1764l * 2304 * 2);
    ushort* obf    = (ushort*)alloc(1764l * 768 * 2);
    float*  tb     = (float*) alloc(1024l * 3072 * 4);
    float*  relh   = (float*) alloc(12l * 1024 * 32 * 4);
    float*  relw   = (float*) alloc(12l * 1024 * 32 * 4);
    ushort* vT     = (ushort*)alloc(108l * 64 * 224 * 2);
    ushort* qkvT   = (ushort*)alloc(12l * 2304 * 768 * 2);
    ushort* projT  = (ushort*)alloc(12l * 768 * 768 * 2);
    ushort* m1T    = (ushort*)alloc(12l * 3072 * 768 * 2);
    ushort* m2T    = (ushort*)alloc(12l * 768 * 3072 * 2);
    ushort* patchbf= (ushort*)alloc(768l * 768 * 2);
    ushort* xc     = (ushort*)alloc(1024l * 768 * 2);
    ushort* xcn    = (ushort*)alloc(1024l * 2304 * 2);
    ushort* hbf    = (ushort*)alloc(1024l * 768 * 2);
    ushort* nw1bf  = (ushort*)alloc(256l * 768 * 2);
    ushort* nw2bf  = (ushort*)alloc(256l * 2304 * 2);
    float*  nk1    = (float*) alloc(1024l * 256 * 4);
    float*  nk2    = (float*) alloc(1024l * 256 * 4);

    // ---- one-time weight converts / batched transposes ----
    cvt_k<<<CDIV(768 * 768, 256), 256, 0, stream>>>(patch_w, patchbf, 768 * 768);
    cvt_k<<<CDIV(256 * 768, 256), 256, 0, stream>>>(neck_w1, nw1bf, 256 * 768);
    cvt_k<<<CDIV(256 * 2304, 256), 256, 0, stream>>>(neck_w2, nw2bf, 256 * 2304);
    wtrans_all_k<<<dim3(2304/32, 768/32, 12),  dim3(32,8), 0, stream>>>(qkv_w,  qkvT, 768, 2304);
    wtrans_all_k<<<dim3(768/32,  768/32, 12),  dim3(32,8), 0, stream>>>(proj_w, projT, 768, 768);
    wtrans_all_k<<<dim3(3072/32, 768/32, 12),  dim3(32,8), 0, stream>>>(mlp1_w, m1T,  768, 3072);
    wtrans_all_k<<<dim3(768/32,  3072/32, 12), dim3(32,8), 0, stream>>>(mlp2_w, m2T, 3072, 768);

    // ---- patch embed ----
    im2col_patch_k<<<CDIV(786432, 256), 256, 0, stream>>>(x, xc);
    mgemm(stream, 64, 1, false, xc, 768, patchbf, 768, h, 768, patch_b, nullptr,
          1024, 768, 768, 1.f, 1, 1, 0, 0, 0, 0, 0, 0);
    add_pos_k<<<CDIV(786432, 256), 256, 0, stream>>>(h, pos);

    int wi = 0, gi = 0;
    for (int i = 0; i < 12; ++i) {
        const bool glb = (i == 2) || (i == 5) || (i == 8) || (i == 11);
        const int S  = glb ? 1024 : 196;
        const int Spad = glb ? 1024 : 224;
        const int nB = glb ? 1 : 9;
        const int ntok = nB * S;
        const int HH = glb ? 32 : 14;
        const int Z  = nB * 12;

        // LN1 (+window partition, zero pad) -> bf16
        ln_part_k<<<ntok, 256, 0, stream>>>(h, ybf, ln1_w + i*768, ln1_b + i*768, glb ? 0 : 1);
        // QKV -> bf16
        mgemm(stream, 128, 1, true, ybf, 768, qkvT + (long)i*2304*768, 768, qkvbf, 2304,
              qkv_b + i*2304, nullptr, ntok, 2304, 768, 1.f, 1, 1, 0, 0, 0, 0, 0, 0);
        // rel-pos dots (unscaled q)
        const float* Rh = glb ? (rhg + (long)gi * 63 * 64) : (rhw + (long)wi * 27 * 64);
        const float* Rw = glb ? (rwg + (long)gi * 63 * 64) : (rww + (long)wi * 27 * 64);
        qrel_k<<<Z * S, 64, 0, stream>>>(qkvbf, Rh, Rw, relh, relw, S, HH, 12);
        // v transpose -> vT[z][64][Spad]
        {
            const int tot = Z * 64 * Spad;
            vT_k<<<CDIV(tot, 256), 256, 0, stream>>>(qkvbf, vT, S, Spad, tot);
        }
        // fused flash attention -> obf
        fattn_k<<<dim3(CDIV(S, 32), Z), 128, 0, stream>>>(
            qkvbf, vT, relh, relw, obf, S, Spad, HH, 12);
        // proj + bias
        mgemm(stream, 64, 1, false, obf, 768, projT + (long)i*768*768, 768, tb, 768,
              proj_b + i*768, nullptr, ntok, 768, 768, 1.f, 1, 1, 0, 0, 0, 0, 0, 0);
        // residual (window unpartition) + LN2 -> bf16 (fused)
        res_ln_k<<<1024, 256, 0, stream>>>(h, tb, glb ? 0 : 1,
                                           ln2_w + i*768, ln2_b + i*768, ybf);
        // MLP
        mgemm(stream, 128, 2, true, ybf, 768, m1T + (long)i*3072*768, 768, tb, 3072,
              mlp1_b + i*3072, nullptr, 1024, 3072, 768, 1.f, 1, 1, 0, 0, 0, 0, 0, 0);
        mgemm(stream, 64, 3, false, (ushort*)tb, 3072, m2T + (long)i*768*3072, 3072, h, 768,
              mlp2_b + i*768, h, 1024, 768, 3072, 1.f, 1, 1, 0, 0, 0, 0, 0, 0);

        if (glb) gi++; else wi++;
    }

    // ---- neck ----
    cvt_k<<<CDIV(786432, 256), 256, 0, stream>>>(h, hbf, 786432);
    mgemm(stream, 64, 0, false, hbf, 768, nw1bf, 768, nk1, 256, nullptr, nullptr,
          1024, 256, 768, 1.f, 1, 1, 0, 0, 0, 0, 0, 0);
    ln2d_k<<<1024, 256, 0, stream>>>(nk1, nk2, nln1_w, nln1_b, 0);
    im2col_neck_k<<<CDIV(1024 * 2304, 256), 256, 0, stream>>>(nk2, xcn);
    mgemm(stream, 64, 0, false, xcn, 2304, nw2bf, 2304, nk1, 256, nullptr, nullptr,
          1024, 256, 2304, 1.f, 1, 1, 0, 0, 0, 0, 0, 0);
    ln2d_k<<<1024, 256, 0, stream>>>(nk1, (float*)d_out, nln2_w, nln2_b, 1);
}